// Round 22
// baseline (2696.616 us; speedup 1.0000x reference)
//
#include <hip/hip_runtime.h>
#include <math.h>

#define DEV __device__ __forceinline__

// ---- problem constants ----
#define PP    256          // pairs
#define BIMG  16
#define HB    712          // bilinear dim
#define KBIL  (712*712)    // 506944
#define KSTEPS (KBIL/32)   // 15842
#define DRELC 1936
#define BSPLIT 16          // bilinear split-K
#define ZPB    991         // z-steps per split (ceil 15842/16; last = 977)
#define KC     16          // z-steps per staging round (512 k = 2KB/row)
#define SLDS   520         // LDS row stride in bf16 (1040 B)

// ---- d_out layout (floats) ----
#define SZ_ACT    (16*157)
#define OFF_ACT   0
#define OFF_POOLED (SZ_ACT)
#define SZ_POOLED (16*1936)
#define OFF_MEM   (OFF_POOLED + SZ_POOLED)
#define SZ_MEM    (24*16*1936)
#define OFF_MASK  (OFF_MEM + SZ_MEM)
#define SZ_MASK   (16*24)

// ---- ws layout (floats) ----
#define OFF_S     0
#define OFF_O     (OFF_S + 256*712)
#define OFF_Z1    (OFF_O + 256*712)
#define OFF_BIL   (OFF_Z1 + 256*712)
#define OFF_REL   (OFF_BIL + 256*712)
#define OFF_UBUF  (OFF_REL + 256*1936)
#define OFF_XP    (OFF_UBUF + 12544*256)
#define OFF_SHARED (OFF_XP + 256*128*49)
#define OFF_X1    OFF_SHARED                       // 256*128*196 floats
#define OFF_PVR   OFF_SHARED                       // 32*256*512 = 4.19M <= 6.42M
// pbil (16*256*712 = 2.92M floats) aliases ubuf region (dead by then);
// lin/proj partials too, consumed before pbil written (stream-ordered).
#define OFF_PBIL  OFF_UBUF
#define OFF_PLIN  OFF_UBUF
#define OFF_PPROJ OFF_UBUF
#define SZ_SHARED (256*128*196)                    // max(x1, pvr)
#define OFF_INTS  (OFF_SHARED + SZ_SHARED)
// bilinear prep buffers: o as bf16 [256][712], sT f32 [712][256]
#define OFF_OB    (OFF_INTS + 256)                 // 256*712 bf16 = 91136 floats
#define OFF_ST    (OFF_OB + 91136)                 // 712*256 floats

typedef __bf16 bf16x4 __attribute__((ext_vector_type(4)));
typedef __bf16 bf16x8 __attribute__((ext_vector_type(8)));
typedef float  f32x4  __attribute__((ext_vector_type(4)));

// ============================================================
// prep: o -> bf16 (row-major [256][712]); s -> transposed sT [712][256].
// ============================================================
__global__ __launch_bounds__(256) void prep_k(const float* __restrict__ s,
    const float* __restrict__ o, __bf16* __restrict__ ob, float* __restrict__ sT) {
  int i = blockIdx.x*256 + threadIdx.x;
  if (i < 256*712) {
    ob[i] = (__bf16)o[i];
  } else {
    int j = i - 256*712;
    if (j < 712*256) {
      int h = j >> 8, n = j & 255;
      sT[j] = s[n*712 + h];
    }
  }
}

// ============================================================
// Bilinear v3.3 — r21 skeleton + DEFERRED-RESCALE accumulation.
// Within a 32-k z-step, h = k/712 is constant except when the step
// straddles k = m*712 (boundaries are multiples of 8; ~4.5% of steps,
// wave-uniform branch). Non-straddling steps: gacc += mfma(o8, b8)
// — PURE bf16x8 loads, ZERO per-step VALU. On h change: flush
// bacc += s[n,h]*gacc (16 FMA + 4 f32x4 loads, once per ~22 steps).
// Straddling steps: per-lane s path directly into bacc (old r21 body).
// Numerics improve vs r21 (s applied exactly in f32; only o is bf16).
// Registers: st 32 + pA/pB 32 + gacc/bacc 32 + addr ~20 ≈ 115 (<170).
// ============================================================
__global__ __launch_bounds__(256, 3) void bil_mfma_k(
    const __bf16* __restrict__ ob, const float* __restrict__ sT,
    const float* __restrict__ W, float* __restrict__ part) {
  __shared__ __align__(16) __bf16 Wsh[2][16*SLDS];   // 2 x 16.6 KB

  const int tid = threadIdx.x;
  const int wv = tid >> 6, lane = tid & 63;
  const int lr = lane & 15, lg = lane >> 4;
  const int c0 = blockIdx.x * 16;
  const int bz = blockIdx.y;
  const int zbase = bz * ZPB;
  const int zcntT = min(ZPB, KSTEPS - zbase);       // 991 or 977
  const int nrounds = (zcntT + KC - 1) / KC;

  // staging role: 16 threads per col-row; thread reads 8 x float4 (2KB/row)
  const int srow = tid >> 4;         // 0..15 = col within tile
  const int sl = tid & 15;
  const int scol = min(c0 + srow, 711);
  const float* wrow = W + (size_t)scol * KBIL;

  // compute role: wave wv owns rows [wv*64, wv*64+64), all 16 cols
  const int n0 = wv * 64;
  const int myc = c0 + lr;

  f32x4 gacc[4], bacc[4];
  #pragma unroll
  for (int rf = 0; rf < 4; rf++) {
    gacc[rf][0]=0.f; gacc[rf][1]=0.f; gacc[rf][2]=0.f; gacc[rf][3]=0.f;
    bacc[rf][0]=0.f; bacc[rf][1]=0.f; bacc[rf][2]=0.f; bacc[rf][3]=0.f;
  }
  int curh = (zbase * 32) / 712;

  float4 st0, st1, st2, st3, st4, st5, st6, st7;
  auto stage_load = [&](int r) {
    const int kb = (zbase + r*KC) * 32 + sl*4;
    #define LD(J, DST) { int k = kb + (J)*64; if (k > KBIL-4) k = KBIL-4; \
                         DST = *(const float4*)(wrow + k); }
    LD(0, st0) LD(1, st1) LD(2, st2) LD(3, st3)
    LD(4, st4) LD(5, st5) LD(6, st6) LD(7, st7)
    #undef LD
  };
  auto stage_store = [&](int buf) {
    __bf16* base = &Wsh[buf][srow*SLDS + sl*4];
    #define ST(J, SRC) { bf16x4 b; b[0]=(__bf16)SRC.x; b[1]=(__bf16)SRC.y; \
                         b[2]=(__bf16)SRC.z; b[3]=(__bf16)SRC.w; \
                         *(bf16x4*)(base + (J)*64) = b; }
    ST(0, st0) ST(1, st1) ST(2, st2) ST(3, st3)
    ST(4, st4) ST(5, st5) ST(6, st6) ST(7, st7)
    #undef ST
  };

#define FLUSH() { \
    f32x4 sv0 = *(const f32x4*)&sT[(size_t)curh*256 + n0 +  0 + lg*4]; \
    f32x4 sv1 = *(const f32x4*)&sT[(size_t)curh*256 + n0 + 16 + lg*4]; \
    f32x4 sv2 = *(const f32x4*)&sT[(size_t)curh*256 + n0 + 32 + lg*4]; \
    f32x4 sv3 = *(const f32x4*)&sT[(size_t)curh*256 + n0 + 48 + lg*4]; \
    _Pragma("unroll") \
    for (int i_ = 0; i_ < 4; i_++) { \
      bacc[0][i_] += sv0[i_]*gacc[0][i_]; gacc[0][i_] = 0.f; \
      bacc[1][i_] += sv1[i_]*gacc[1][i_]; gacc[1][i_] = 0.f; \
      bacc[2][i_] += sv2[i_]*gacc[2][i_]; gacc[2][i_] = 0.f; \
      bacc[3][i_] += sv3[i_]*gacc[3][i_]; gacc[3][i_] = 0.f; } }

  // ---- prologue ----
  stage_load(0);
  stage_store(0);
  if (nrounds > 1) stage_load(1);
  __syncthreads();

  // ---- main loop: one barrier per 16-step round ----
  for (int r = 0; r < nrounds; ++r) {
    const int zr0 = zbase + r*KC;
    const int zc = min(KC, zbase + zcntT - zr0);
    const int buf = r & 1;

#define LOADO(ZS, O0,O1,O2,O3) { \
      const int kk_ = (zr0 + (ZS))*32 + lg*8; \
      const int h_ = kk_ / 712; \
      const int t_ = kk_ - h_*712; \
      O0 = *(const bf16x8*)&ob[(size_t)(n0 +  0 + lr)*712 + t_]; \
      O1 = *(const bf16x8*)&ob[(size_t)(n0 + 16 + lr)*712 + t_]; \
      O2 = *(const bf16x8*)&ob[(size_t)(n0 + 32 + lr)*712 + t_]; \
      O3 = *(const bf16x8*)&ob[(size_t)(n0 + 48 + lr)*712 + t_]; }

#define STEPX(ZS, O0,O1,O2,O3) { \
      bf16x8 b8 = *(const bf16x8*)&Wsh[buf][lr*SLDS + (ZS)*32 + lg*8]; \
      const int kk0_ = (zr0 + (ZS))*32; \
      const int ha_ = kk0_ / 712; \
      const int hb_ = (kk0_ + 31) / 712; \
      if (ha_ == hb_) { \
        if (ha_ != curh) { FLUSH(); curh = ha_; } \
        gacc[0] = __builtin_amdgcn_mfma_f32_16x16x32_bf16(O0, b8, gacc[0], 0, 0, 0); \
        gacc[1] = __builtin_amdgcn_mfma_f32_16x16x32_bf16(O1, b8, gacc[1], 0, 0, 0); \
        gacc[2] = __builtin_amdgcn_mfma_f32_16x16x32_bf16(O2, b8, gacc[2], 0, 0, 0); \
        gacc[3] = __builtin_amdgcn_mfma_f32_16x16x32_bf16(O3, b8, gacc[3], 0, 0, 0); \
      } else { \
        const int hl_ = (kk0_ + lg*8) / 712; \
        bf16x8 a8; float sv; \
        sv = sT[hl_*256 + n0 +  0 + lr]; \
        _Pragma("unroll") for (int i_=0;i_<8;i_++) a8[i_]=(__bf16)(sv*(float)O0[i_]); \
        bacc[0] = __builtin_amdgcn_mfma_f32_16x16x32_bf16(a8, b8, bacc[0], 0, 0, 0); \
        sv = sT[hl_*256 + n0 + 16 + lr]; \
        _Pragma("unroll") for (int i_=0;i_<8;i_++) a8[i_]=(__bf16)(sv*(float)O1[i_]); \
        bacc[1] = __builtin_amdgcn_mfma_f32_16x16x32_bf16(a8, b8, bacc[1], 0, 0, 0); \
        sv = sT[hl_*256 + n0 + 32 + lr]; \
        _Pragma("unroll") for (int i_=0;i_<8;i_++) a8[i_]=(__bf16)(sv*(float)O2[i_]); \
        bacc[2] = __builtin_amdgcn_mfma_f32_16x16x32_bf16(a8, b8, bacc[2], 0, 0, 0); \
        sv = sT[hl_*256 + n0 + 48 + lr]; \
        _Pragma("unroll") for (int i_=0;i_<8;i_++) a8[i_]=(__bf16)(sv*(float)O3[i_]); \
        bacc[3] = __builtin_amdgcn_mfma_f32_16x16x32_bf16(a8, b8, bacc[3], 0, 0, 0); \
      } }

    if (zc == KC) {
      // ping-pong prefetch: pure ob loads issued one step ahead
      bf16x8 pA0, pA1, pA2, pA3, pB0, pB1, pB2, pB3;
      LOADO(0, pA0,pA1,pA2,pA3)
      LOADO(1, pB0,pB1,pB2,pB3)
      for (int zs = 0; zs + 3 < KC; zs += 2) {
        STEPX(zs,   pA0,pA1,pA2,pA3)
        LOADO(zs+2, pA0,pA1,pA2,pA3)
        STEPX(zs+1, pB0,pB1,pB2,pB3)
        LOADO(zs+3, pB0,pB1,pB2,pB3)
      }
      STEPX(KC-2, pA0,pA1,pA2,pA3)
      STEPX(KC-1, pB0,pB1,pB2,pB3)
    } else {
      // tail round (last round of last bz)
      for (int zs = 0; zs < zc; ++zs) {
        bf16x8 t0, t1, t2, t3;
        LOADO(zs, t0,t1,t2,t3)
        STEPX(zs, t0,t1,t2,t3)
      }
    }
#undef LOADO
#undef STEPX

    if (r + 1 < nrounds) {
      stage_store((r+1)&1);          // writes buffer NOT being computed
      __syncthreads();
      if (r + 2 < nrounds) stage_load(r+2);
    }
  }

  FLUSH();                            // drain pending gacc
#undef FLUSH

  // ---- epilogue: partials [bz][256][712] (D: col=lane&15, row=(lane>>4)*4+i)
  if (myc < 712) {
    #pragma unroll
    for (int rf = 0; rf < 4; rf++) {
      #pragma unroll
      for (int i = 0; i < 4; i++) {
        const int n = n0 + rf*16 + lg*4 + i;
        part[((size_t)bz*256 + n)*712 + myc] = bacc[rf][i];
      }
    }
  }
}

struct GP {
  const float* A; const float* A2; const float* B; const float* bias;
  float* C;
  const int* gidx; int goff;
  int M, N, K;
  int ldc, coff;
  int kChunk;
  const float* bn_g; const float* bn_b; const float* bn_m; const float* bn_v;
  const float* B2; const float* bias2; float* C2;   // mode 0 pair-merge
};

// modes:
// 0: A gathered via gidx col=blockIdx.z; B/bias/C selected by blockIdx.z
// 2: plain A (ubuf rows), plain B (vr_w)        epi: partial C[z][M][N]
// 3: A = concat(s,o)                            epi: partial C[z][M][N]
// 4: A = relu(concat(z1,bil))                   epi: partial C[z][M][N]
// 5: A = union_feat gather [(n,q)][ic]          epi: +bias -> ubuf[n][oc][q]
// 6: A = im2col(xp) 3x3 pad1                    epi: bn2(relu(+bias)) += ubuf[n][oc][q]
// 8: plain A                                    epi: sigmoid(+bias) -> C

template<int MODE>
DEV float loadA(const GP& p, int r, int k) {
  if (MODE == 0) { int fr = p.gidx[2*r + (int)blockIdx.z]; return p.A[fr*2048 + k]; }
  if (MODE == 2 || MODE == 8) return p.A[r*p.K + k];
  if (MODE == 3) return (k < 712) ? p.A[r*712 + k] : p.A2[r*712 + (k-712)];
  if (MODE == 4) { float v = (k < 712) ? p.A[r*712 + k] : p.A2[r*712 + (k-712)];
                   return fmaxf(v, 0.f); }
  if (MODE == 5) { int n = r/49, q = r - n*49; return p.A[(n*1024 + k)*49 + q]; }
  if (MODE == 6) {
    int n = r/49, q = r - n*49; int py = q/7, px = q - py*7;
    int ic = k/9, k9 = k - ic*9; int dy = k9/3, dx = k9 - dy*3;
    int iy = py + dy - 1, ix = px + dx - 1;
    if ((unsigned)iy >= 7u || (unsigned)ix >= 7u) return 0.f;
    return p.A[(n*128 + ic)*49 + iy*7 + ix];
  }
  return 0.f;
}

template<int MODE>
DEV float loadB(const GP& p, int c, int k) {
  if (MODE == 0) { const float* Bp = blockIdx.z ? p.B2 : p.B; return Bp[c*p.K + k]; }
  return p.B[c*p.K + k];
}

// ============================================================
// Generic GEMM, bf16-split MFMA (3-term, unchanged from r10-r21).
// ============================================================
template<int MODE>
__global__ __launch_bounds__(256) void gemm_k(GP p) {
  __shared__ __align__(16) __bf16 Ash[2][64*44];
  __shared__ __align__(16) __bf16 Bsh[2][64*44];
  const int tid = threadIdx.x;
  const int srow = tid & 63, koff = (tid >> 6) * 8;
  const int col0 = blockIdx.x * 64, row0 = blockIdx.y * 64;
  const int kStart = (MODE == 0) ? 0 : blockIdx.z * p.kChunk;
  const int kEnd = min(p.K, kStart + p.kChunk);
  const int wv = tid >> 6, lane = tid & 63;
  const int lr = lane & 15, lg = lane >> 4;
  const int rh = wv >> 1, ch = wv & 1;

  f32x4 acc[2][2];
  #pragma unroll
  for (int a = 0; a < 2; a++)
    #pragma unroll
    for (int b = 0; b < 2; b++) { acc[a][b][0]=0.f; acc[a][b][1]=0.f; acc[a][b][2]=0.f; acc[a][b][3]=0.f; }

  for (int kb = kStart; kb < kEnd; kb += 32) {
    {
      const int gr = row0 + srow;
      float v[8];
      #pragma unroll
      for (int i = 0; i < 8; i++) {
        const int gk = kb + koff + i;
        v[i] = (gr < p.M && gk < kEnd) ? loadA<MODE>(p, gr, gk) : 0.f;
      }
      bf16x8 hi, lo;
      #pragma unroll
      for (int i = 0; i < 8; i++) {
        __bf16 h = (__bf16)v[i];
        hi[i] = h;
        lo[i] = (__bf16)(v[i] - (float)h);
      }
      *(bf16x8*)&Ash[0][srow*44 + koff] = hi;
      *(bf16x8*)&Ash[1][srow*44 + koff] = lo;
    }
    {
      const int gc = col0 + srow;
      float v[8];
      #pragma unroll
      for (int i = 0; i < 8; i++) {
        const int gk = kb + koff + i;
        v[i] = (gc < p.N && gk < kEnd) ? loadB<MODE>(p, gc, gk) : 0.f;
      }
      bf16x8 hi, lo;
      #pragma unroll
      for (int i = 0; i < 8; i++) {
        __bf16 h = (__bf16)v[i];
        hi[i] = h;
        lo[i] = (__bf16)(v[i] - (float)h);
      }
      *(bf16x8*)&Bsh[0][srow*44 + koff] = hi;
      *(bf16x8*)&Bsh[1][srow*44 + koff] = lo;
    }
    __syncthreads();
    #pragma unroll
    for (int rf = 0; rf < 2; rf++) {
      bf16x8 ahi = *(const bf16x8*)&Ash[0][(rh*32 + rf*16 + lr)*44 + lg*8];
      bf16x8 alo = *(const bf16x8*)&Ash[1][(rh*32 + rf*16 + lr)*44 + lg*8];
      #pragma unroll
      for (int cf = 0; cf < 2; cf++) {
        bf16x8 bhi = *(const bf16x8*)&Bsh[0][(ch*32 + cf*16 + lr)*44 + lg*8];
        bf16x8 blo = *(const bf16x8*)&Bsh[1][(ch*32 + cf*16 + lr)*44 + lg*8];
        acc[rf][cf] = __builtin_amdgcn_mfma_f32_16x16x32_bf16(ahi, bhi, acc[rf][cf], 0, 0, 0);
        acc[rf][cf] = __builtin_amdgcn_mfma_f32_16x16x32_bf16(ahi, blo, acc[rf][cf], 0, 0, 0);
        acc[rf][cf] = __builtin_amdgcn_mfma_f32_16x16x32_bf16(alo, bhi, acc[rf][cf], 0, 0, 0);
      }
    }
    __syncthreads();
  }

  // ---- epilogue (D: col=lane&15, row=(lane>>4)*4+i) ----
  #pragma unroll
  for (int rf = 0; rf < 2; rf++) {
    #pragma unroll
    for (int cf = 0; cf < 2; cf++) {
      const int c = col0 + ch*32 + cf*16 + lr;
      if (c >= p.N) continue;
      #pragma unroll
      for (int i = 0; i < 4; i++) {
        const int r = row0 + rh*32 + rf*16 + lg*4 + i;
        if (r >= p.M) continue;
        float v = acc[rf][cf][i];
        if (MODE == 2 || MODE == 3 || MODE == 4) {
          p.C[(size_t)blockIdx.z * p.M * p.N + (size_t)r * p.N + c] = v;
        } else if (MODE == 5) {
          int n = r/49, q = r - n*49;
          p.C[n*12544 + c*49 + q] = v + p.bias[c];
        } else if (MODE == 6) {
          int n = r/49, q = r - n*49;
          float sc = p.bn_g[c] / sqrtf(p.bn_v[c] + 1e-5f);
          float sh = p.bn_b[c] - p.bn_m[c]*sc;
          float t2 = fmaxf(v + p.bias[c], 0.f)*sc + sh;
          p.C[n*12544 + c*49 + q] += t2;
        } else if (MODE == 8) {
          float t2 = v + p.bias[c];
          p.C[r*p.ldc + p.coff + c] = 1.f/(1.f + expf(-t2));
        } else {  // MODE 0: pair-merged subj/obj
          const float* bb = blockIdx.z ? p.bias2 : p.bias;
          float* Cp = blockIdx.z ? p.C2 : p.C;
          Cp[r*p.ldc + p.coff + c] = v + bb[c];
        }
      }
    }
  }
}

__global__ __launch_bounds__(256) void reduce_k(const float* __restrict__ part,
    const float* __restrict__ bias, float* __restrict__ out,
    int S, int MN, int N, int ldc, int coff) {
  int i = blockIdx.x*256 + threadIdx.x;
  if (i >= MN) return;
  float s = 0.f;
  for (int z = 0; z < S; z++) s += part[(size_t)z*MN + i];
  int r = i / N, c = i - r*N;
  out[r*ldc + coff + c] = s + bias[c];
}

__global__ __launch_bounds__(256) void emb_k(const int* __restrict__ pi,
    const int* __restrict__ labels, const float* __restrict__ e1,
    const float* __restrict__ e2, float* __restrict__ s, float* __restrict__ o) {
  int i = blockIdx.x*256 + threadIdx.x;
  if (i >= 2*256*200) return;
  int which = i / (256*200); int rest = i - which*(256*200);
  int n = rest / 200; int j = rest - n*200;
  int lab = labels[pi[2*n + which]];
  float v = which ? e2[lab*200 + j] : e1[lab*200 + j];
  (which ? o : s)[n*712 + 512 + j] = v;
}

__global__ __launch_bounds__(256) void conv1_k(const float* __restrict__ in,
    const float* __restrict__ w, const float* __restrict__ bias,
    const float* __restrict__ g, const float* __restrict__ bt,
    const float* __restrict__ m, const float* __restrict__ vv,
    float* __restrict__ out) {
  int idx = blockIdx.x*256 + threadIdx.x;
  if (idx >= 256*128*14) return;
  int oy = idx % 14; int t = idx / 14; int c = t & 127; int n = t >> 7;
  float acc[14];
  float b0 = bias[c];
  #pragma unroll
  for (int ox = 0; ox < 14; ox++) acc[ox] = b0;
  for (int ci = 0; ci < 2; ci++) {
    #pragma unroll
    for (int ky = 0; ky < 7; ky++) {
      int iy = oy*2 - 3 + ky;
      if ((unsigned)iy >= 27u) continue;
      const float* ir = in + ((n*2 + ci)*27 + iy)*27;
      const float* wr = w + ((c*2 + ci)*7 + ky)*7;
      float iv[27];
      #pragma unroll
      for (int x = 0; x < 27; x++) iv[x] = ir[x];
      float wk[7];
      #pragma unroll
      for (int kx = 0; kx < 7; kx++) wk[kx] = wr[kx];
      #pragma unroll
      for (int kx = 0; kx < 7; kx++)
        #pragma unroll
        for (int ox = 0; ox < 14; ox++) {
          int ix = ox*2 - 3 + kx;
          if (ix >= 0 && ix < 27) acc[ox] += iv[ix]*wk[kx];
        }
    }
  }
  float sc = g[c] / sqrtf(vv[c] + 1e-5f);
  float sh = bt[c] - m[c]*sc;
  float* orow = out + ((n*128 + c)*14 + oy)*14;
  #pragma unroll
  for (int ox = 0; ox < 14; ox++) orow[ox] = fmaxf(acc[ox], 0.f)*sc + sh;
}

__global__ __launch_bounds__(256) void pool_k(const float* __restrict__ x1,
                                              float* __restrict__ xp) {
  int idx = blockIdx.x*256 + threadIdx.x;
  if (idx >= 256*128*49) return;
  int px = idx % 7; int t = idx / 7; int py = t % 7; t /= 7;
  int c = t & 127; int n = t >> 7;
  float mx = -INFINITY;
  for (int dy = 0; dy < 3; dy++) {
    int y = py*2 - 1 + dy;
    if ((unsigned)y >= 14u) continue;
    for (int dx = 0; dx < 3; dx++) {
      int x = px*2 - 1 + dx;
      if ((unsigned)x >= 14u) continue;
      mx = fmaxf(mx, x1[((n*128 + c)*14 + y)*14 + x]);
    }
  }
  xp[((n*128 + c)*7 + py)*7 + px] = mx;
}

__global__ __launch_bounds__(256) void seg_k(const int* __restrict__ im,
    int* __restrict__ counts, int* __restrict__ starts, int* __restrict__ pos) {
  __shared__ int c[16], s[16];
  int tid = threadIdx.x;
  if (tid < 16) c[tid] = 0;
  __syncthreads();
  atomicAdd(&c[im[tid]], 1);
  __syncthreads();
  if (tid == 0) { int run = 0; for (int b = 0; b < 16; b++) { s[b] = run; run += c[b]; } }
  __syncthreads();
  if (tid < 16) { counts[tid] = c[tid]; starts[tid] = s[tid]; }
  pos[tid] = tid - s[im[tid]];
}

__global__ __launch_bounds__(256) void zeromask_k(float* __restrict__ out,
                                                  const int* __restrict__ counts) {
  int i = blockIdx.x*256 + threadIdx.x;
  if (i < SZ_MEM) { out[OFF_MEM + i] = 0.f; return; }
  int j = i - SZ_MEM;
  if (j < SZ_MASK) {
    int b = j / 24, l = j - b*24;
    out[OFF_MASK + j] = (l >= counts[b]) ? 1.f : 0.f;
  }
}

__global__ __launch_bounds__(256) void scatter_k(const float* __restrict__ rel,
    const int* __restrict__ pos, const int* __restrict__ im, float* __restrict__ out) {
  int n = blockIdx.x;
  int l = pos[n], b = im[n];
  float* dst = out + OFF_MEM + ((size_t)l*16 + b)*1936;
  const float* src = rel + (size_t)n*1936;
  for (int d = threadIdx.x; d < 1936; d += 256) dst[d] = src[d];
}

__global__ __launch_bounds__(256) void pooled_k(const float* __restrict__ rel,
    const int* __restrict__ starts, const int* __restrict__ counts,
    float* __restrict__ out) {
  int b = blockIdx.y;
  int d = blockIdx.x*256 + threadIdx.x;
  if (d >= 1936) return;
  int st = starts[b], ct = counts[b];
  float mx = -INFINITY;
  for (int i = 0; i < ct; i++) mx = fmaxf(mx, rel[(size_t)(st + i)*1936 + d]);
  out[OFF_POOLED + b*1936 + d] = mx;
}

extern "C" void kernel_launch(void* const* d_in, const int* in_sizes, int n_in,
                              void* d_out, int out_size, void* d_ws, size_t ws_size,
                              hipStream_t stream) {
  const float* features   = (const float*)d_in[0];
  const int*   pair_idx   = (const int*)d_in[1];
  const int*   im_idx     = (const int*)d_in[2];
  const int*   labels     = (const int*)d_in[3];
  const float* union_feat = (const float*)d_in[4];
  const float* spatial    = (const float*)d_in[5];
  const float* w_union    = (const float*)d_in[6];
  const float* b_union    = (const float*)d_in[7];
  const float* conv1_w    = (const float*)d_in[8];
  const float* conv1_b    = (const float*)d_in[9];
  const float* bn1_g      = (const float*)d_in[10];
  const float* bn1_b      = (const float*)d_in[11];
  const float* bn1_m      = (const float*)d_in[12];
  const float* bn1_v      = (const float*)d_in[13];
  const float* conv2_w    = (const float*)d_in[14];
  const float* conv2_b    = (const float*)d_in[15];
  const float* bn2_g      = (const float*)d_in[16];
  const float* bn2_b      = (const float*)d_in[17];
  const float* bn2_m      = (const float*)d_in[18];
  const float* bn2_v      = (const float*)d_in[19];
  const float* subj_w     = (const float*)d_in[20];
  const float* subj_b     = (const float*)d_in[21];
  const float* obj_w      = (const float*)d_in[22];
  const float* obj_b      = (const float*)d_in[23];
  const float* vr_w       = (const float*)d_in[24];
  const float* vr_b       = (const float*)d_in[25];
  const float* emb1       = (const float*)d_in[26];
  const float* emb2       = (const float*)d_in[27];
  const float* bil_w      = (const float*)d_in[28];
  const float* bil_b      = (const float*)d_in[29];
  const float* lin_w      = (const float*)d_in[30];
  const float* lin_b      = (const float*)d_in[31];
  const float* proj_w     = (const float*)d_in[32];
  const float* proj_b     = (const float*)d_in[33];
  const float* ac_w       = (const float*)d_in[34];
  const float* ac_b       = (const float*)d_in[35];

  float* ws = (float*)d_ws;
  float* s_mat  = ws + OFF_S;
  float* o_mat  = ws + OFF_O;
  float* z1     = ws + OFF_Z1;
  float* bilbuf = ws + OFF_BIL;
  float* rel    = ws + OFF_REL;
  float* ubuf   = ws + OFF_UBUF;   // layout [n][oc][q] = [256][256][49]
  float* x1     = ws + OFF_X1;
  float* xp     = ws + OFF_XP;
  float* pvr    = ws + OFF_PVR;
  float* pbil   = ws + OFF_PBIL;
  float* plin   = ws + OFF_PLIN;
  float* pproj  = ws + OFF_PPROJ;
  int*   ints   = (int*)(ws + OFF_INTS);
  __bf16* obp   = (__bf16*)(ws + OFF_OB);
  float* sTp    = ws + OFF_ST;
  int* counts = ints; int* starts = ints + 16; int* pos = ints + 32;
  float* out = (float*)d_out;

  dim3 blk(256);

  // subj + obj linears in ONE dispatch (blockIdx.z selects weights/output)
  {
    GP g{}; g.A = features; g.gidx = pair_idx;
    g.B = subj_w;  g.bias = subj_b;  g.C = s_mat;
    g.B2 = obj_w;  g.bias2 = obj_b;  g.C2 = o_mat;
    g.M = 256; g.N = 512; g.K = 2048; g.ldc = 712; g.coff = 0; g.kChunk = 2048;
    gemm_k<0><<<dim3(8,4,2), blk, 0, stream>>>(g);
  }
  // embedding concat -> cols [512,712)
  emb_k<<<dim3(400), blk, 0, stream>>>(pair_idx, labels, emb1, emb2, s_mat, o_mat);

  // union 1x1 conv as GEMM -> ubuf[n][oc][q] (scatter epilogue)
  {
    GP g{}; g.A = union_feat; g.B = w_union; g.bias = b_union; g.C = ubuf;
    g.M = 12544; g.N = 256; g.K = 1024; g.kChunk = 1024;
    gemm_k<5><<<dim3(4,196,1), blk, 0, stream>>>(g);
  }

  // conv1 + relu + bn1 -> x1 ; maxpool -> xp
  conv1_k<<<dim3(1792), blk, 0, stream>>>(spatial, conv1_w, conv1_b,
                                          bn1_g, bn1_b, bn1_m, bn1_v, x1);
  pool_k<<<dim3(6272), blk, 0, stream>>>(x1, xp);

  // conv2 (implicit GEMM) + relu + bn2, accumulated into ubuf[n][oc][q]
  {
    GP g{}; g.A = xp; g.B = conv2_w; g.bias = conv2_b; g.C = ubuf;
    g.M = 12544; g.N = 256; g.K = 1152; g.kChunk = 1152;
    g.bn_g = bn2_g; g.bn_b = bn2_b; g.bn_m = bn2_m; g.bn_v = bn2_v;
    gemm_k<6><<<dim3(4,196,1), blk, 0, stream>>>(g);
  }

  // vr linear: split-K 32 -> partials -> rel[:,1424:1936]
  {
    GP g{}; g.A = ubuf; g.B = vr_w; g.C = pvr;
    g.M = 256; g.N = 512; g.K = 12544; g.kChunk = 392;
    gemm_k<2><<<dim3(8,4,32), blk, 0, stream>>>(g);
    reduce_k<<<dim3(512), blk, 0, stream>>>(pvr, vr_b, rel, 32, 256*512, 512, 1936, 1424);
  }

  // lin: concat(s,o) @ lin_w^T, split-K 4 -> partials -> z1
  {
    GP g{}; g.A = s_mat; g.A2 = o_mat; g.B = lin_w; g.C = plin;
    g.M = 256; g.N = 712; g.K = 1424; g.kChunk = 356;
    gemm_k<3><<<dim3(12,4,4), blk, 0, stream>>>(g);
    reduce_k<<<dim3(712), blk, 0, stream>>>(plin, lin_b, z1, 4, 256*712, 712, 712, 0);
  }

  // bilinear: prep, burst-staged MFMA + deferred-rescale + ping-pong
  prep_k<<<dim3((256*712 + 712*256 + 255)/256), blk, 0, stream>>>(s_mat, o_mat, obp, sTp);
  bil_mfma_k<<<dim3(45, BSPLIT), blk, 0, stream>>>(obp, sTp, bil_w, pbil);
  reduce_k<<<dim3(712), blk, 0, stream>>>(pbil, bil_b, bilbuf, BSPLIT, 256*712, 712, 712, 0);

  // proj: relu(concat(z1,bil)) @ proj_w^T, split-K 2 -> partials -> rel[:,0:1424]
  {
    GP g{}; g.A = z1; g.A2 = bilbuf; g.B = proj_w; g.C = pproj;
    g.M = 256; g.N = 1424; g.K = 1424; g.kChunk = 712;
    gemm_k<4><<<dim3(23,4,2), blk, 0, stream>>>(g);
    reduce_k<<<dim3(1424), blk, 0, stream>>>(pproj, proj_b, rel, 2, 256*1424, 1424, 1936, 0);
  }

  // segments, memory zero + mask, scatter, pooled max
  seg_k<<<dim3(1), blk, 0, stream>>>(im_idx, counts, starts, pos);
  zeromask_k<<<dim3((SZ_MEM + SZ_MASK + 255)/256), blk, 0, stream>>>(out, counts);
  scatter_k<<<dim3(256), blk, 0, stream>>>(rel, pos, im_idx, out);
  pooled_k<<<dim3(8,16), blk, 0, stream>>>(rel, starts, counts, out);

  // act = sigmoid(pooled @ ac_w^T + ac_b)
  {
    GP g{}; g.A = out + OFF_POOLED; g.B = ac_w; g.bias = ac_b; g.C = out + OFF_ACT;
    g.M = 16; g.N = 157; g.K = 1936; g.ldc = 157; g.coff = 0; g.kChunk = 1936;
    gemm_k<8><<<dim3(3,1,1), blk, 0, stream>>>(g);
  }
}

// Round 23
// 2091.197 us; speedup vs baseline: 1.2895x; 1.2895x over previous
//
#include <hip/hip_runtime.h>
#include <math.h>

#define DEV __device__ __forceinline__

// ---- problem constants ----
#define PP    256          // pairs
#define BIMG  16
#define HB    712          // bilinear dim
#define KBIL  (712*712)    // 506944
#define KSTEPS (KBIL/32)   // 15842
#define DRELC 1936
#define BSPLIT 16          // bilinear split-K
#define ZPB    991         // z-steps per split (ceil 15842/16; last = 977)
#define KC     16          // z-steps per staging round (512 k = 2KB/row)
#define SLDS   520         // LDS row stride in bf16 (1040 B)

// ---- d_out layout (floats) ----
#define SZ_ACT    (16*157)
#define OFF_ACT   0
#define OFF_POOLED (SZ_ACT)
#define SZ_POOLED (16*1936)
#define OFF_MEM   (OFF_POOLED + SZ_POOLED)
#define SZ_MEM    (24*16*1936)
#define OFF_MASK  (OFF_MEM + SZ_MEM)
#define SZ_MASK   (16*24)

// ---- ws layout (floats) ----
#define OFF_S     0
#define OFF_O     (OFF_S + 256*712)
#define OFF_Z1    (OFF_O + 256*712)
#define OFF_BIL   (OFF_Z1 + 256*712)
#define OFF_REL   (OFF_BIL + 256*712)
#define OFF_UBUF  (OFF_REL + 256*1936)
#define OFF_XP    (OFF_UBUF + 12544*256)
#define OFF_SHARED (OFF_XP + 256*128*49)
#define OFF_X1    OFF_SHARED                       // 256*128*196 floats
#define OFF_PVR   OFF_SHARED                       // 32*256*512 = 4.19M <= 6.42M
// pbil (16*256*712 = 2.92M floats) aliases ubuf region (dead by then);
// lin/proj partials too, consumed before pbil written (stream-ordered).
#define OFF_PBIL  OFF_UBUF
#define OFF_PLIN  OFF_UBUF
#define OFF_PPROJ OFF_UBUF
#define SZ_SHARED (256*128*196)                    // max(x1, pvr)
#define OFF_INTS  (OFF_SHARED + SZ_SHARED)
// bilinear prep buffers: o as bf16 [256][712], sT f32 [712][256]
#define OFF_OB    (OFF_INTS + 256)                 // 256*712 bf16 = 91136 floats
#define OFF_ST    (OFF_OB + 91136)                 // 712*256 floats

typedef __bf16 bf16x4 __attribute__((ext_vector_type(4)));
typedef __bf16 bf16x8 __attribute__((ext_vector_type(8)));
typedef float  f32x4  __attribute__((ext_vector_type(4)));

// ============================================================
// prep: o -> bf16 (row-major [256][712]); s -> transposed sT [712][256].
// ============================================================
__global__ __launch_bounds__(256) void prep_k(const float* __restrict__ s,
    const float* __restrict__ o, __bf16* __restrict__ ob, float* __restrict__ sT) {
  int i = blockIdx.x*256 + threadIdx.x;
  if (i < 256*712) {
    ob[i] = (__bf16)o[i];
  } else {
    int j = i - 256*712;
    if (j < 712*256) {
      int h = j >> 8, n = j & 255;
      sT[j] = s[n*712 + h];
    }
  }
}

// ============================================================
// Bilinear v3.2 (round-21 VERBATIM — measured best: bil 1173 us,
// total 2091 us, VGPR 76, no spill). Burst-staged W + ping-pong
// A-prefetch. r22's deferred-rescale (doubled accumulator) spilled
// (WRITE 1.39GB); this configuration is the feasible-edge optimum.
// ============================================================
__global__ __launch_bounds__(256, 3) void bil_mfma_k(
    const __bf16* __restrict__ ob, const float* __restrict__ sT,
    const float* __restrict__ W, float* __restrict__ part) {
  __shared__ __align__(16) __bf16 Wsh[2][16*SLDS];   // 2 x 16.6 KB

  const int tid = threadIdx.x;
  const int wv = tid >> 6, lane = tid & 63;
  const int lr = lane & 15, lg = lane >> 4;
  const int c0 = blockIdx.x * 16;
  const int bz = blockIdx.y;
  const int zbase = bz * ZPB;
  const int zcntT = min(ZPB, KSTEPS - zbase);       // 991 or 977
  const int nrounds = (zcntT + KC - 1) / KC;

  // staging role: 16 threads per col-row; thread reads 8 x float4 (2KB/row)
  const int srow = tid >> 4;         // 0..15 = col within tile
  const int sl = tid & 15;
  const int scol = min(c0 + srow, 711);
  const float* wrow = W + (size_t)scol * KBIL;

  // compute role: wave wv owns rows [wv*64, wv*64+64), all 16 cols
  const int n0 = wv * 64;
  const int myc = c0 + lr;

  f32x4 acc[4];
  #pragma unroll
  for (int rf = 0; rf < 4; rf++) { acc[rf][0]=0.f; acc[rf][1]=0.f; acc[rf][2]=0.f; acc[rf][3]=0.f; }

  float4 st0, st1, st2, st3, st4, st5, st6, st7;
  auto stage_load = [&](int r) {
    const int kb = (zbase + r*KC) * 32 + sl*4;
    #define LD(J, DST) { int k = kb + (J)*64; if (k > KBIL-4) k = KBIL-4; \
                         DST = *(const float4*)(wrow + k); }
    LD(0, st0) LD(1, st1) LD(2, st2) LD(3, st3)
    LD(4, st4) LD(5, st5) LD(6, st6) LD(7, st7)
    #undef LD
  };
  auto stage_store = [&](int buf) {
    __bf16* base = &Wsh[buf][srow*SLDS + sl*4];
    #define ST(J, SRC) { bf16x4 b; b[0]=(__bf16)SRC.x; b[1]=(__bf16)SRC.y; \
                         b[2]=(__bf16)SRC.z; b[3]=(__bf16)SRC.w; \
                         *(bf16x4*)(base + (J)*64) = b; }
    ST(0, st0) ST(1, st1) ST(2, st2) ST(3, st3)
    ST(4, st4) ST(5, st5) ST(6, st6) ST(7, st7)
    #undef ST
  };

  // ---- prologue ----
  stage_load(0);
  stage_store(0);
  if (nrounds > 1) stage_load(1);
  __syncthreads();

  // ---- main loop: one barrier per 16-step round ----
  for (int r = 0; r < nrounds; ++r) {
    const int zr0 = zbase + r*KC;
    const int zc = min(KC, zbase + zcntT - zr0);
    const int buf = r & 1;

#define LOADO(ZS, O0,O1,O2,O3, S0,S1,S2,S3) { \
      const int kk_ = (zr0 + (ZS))*32 + lg*8; \
      const int h_ = kk_ / 712; \
      const int t_ = kk_ - h_*712; \
      O0 = *(const bf16x8*)&ob[(size_t)(n0 +  0 + lr)*712 + t_]; \
      O1 = *(const bf16x8*)&ob[(size_t)(n0 + 16 + lr)*712 + t_]; \
      O2 = *(const bf16x8*)&ob[(size_t)(n0 + 32 + lr)*712 + t_]; \
      O3 = *(const bf16x8*)&ob[(size_t)(n0 + 48 + lr)*712 + t_]; \
      S0 = sT[h_*256 + n0 +  0 + lr]; \
      S1 = sT[h_*256 + n0 + 16 + lr]; \
      S2 = sT[h_*256 + n0 + 32 + lr]; \
      S3 = sT[h_*256 + n0 + 48 + lr]; }

#define STEPX(ZS, O0,O1,O2,O3, S0,S1,S2,S3) { \
      bf16x8 b8 = *(const bf16x8*)&Wsh[buf][lr*SLDS + (ZS)*32 + lg*8]; \
      bf16x8 a8; \
      _Pragma("unroll") \
      for (int i = 0; i < 8; i++) a8[i] = (__bf16)(S0 * (float)O0[i]); \
      acc[0] = __builtin_amdgcn_mfma_f32_16x16x32_bf16(a8, b8, acc[0], 0, 0, 0); \
      _Pragma("unroll") \
      for (int i = 0; i < 8; i++) a8[i] = (__bf16)(S1 * (float)O1[i]); \
      acc[1] = __builtin_amdgcn_mfma_f32_16x16x32_bf16(a8, b8, acc[1], 0, 0, 0); \
      _Pragma("unroll") \
      for (int i = 0; i < 8; i++) a8[i] = (__bf16)(S2 * (float)O2[i]); \
      acc[2] = __builtin_amdgcn_mfma_f32_16x16x32_bf16(a8, b8, acc[2], 0, 0, 0); \
      _Pragma("unroll") \
      for (int i = 0; i < 8; i++) a8[i] = (__bf16)(S3 * (float)O3[i]); \
      acc[3] = __builtin_amdgcn_mfma_f32_16x16x32_bf16(a8, b8, acc[3], 0, 0, 0); }

    if (zc == KC) {
      // ping-pong prefetch: loads issued one step ahead of consumption
      bf16x8 pA0, pA1, pA2, pA3, pB0, pB1, pB2, pB3;
      float  qA0, qA1, qA2, qA3, qB0, qB1, qB2, qB3;
      LOADO(0, pA0,pA1,pA2,pA3, qA0,qA1,qA2,qA3)
      LOADO(1, pB0,pB1,pB2,pB3, qB0,qB1,qB2,qB3)
      for (int zs = 0; zs + 3 < KC; zs += 2) {
        STEPX(zs,   pA0,pA1,pA2,pA3, qA0,qA1,qA2,qA3)
        LOADO(zs+2, pA0,pA1,pA2,pA3, qA0,qA1,qA2,qA3)
        STEPX(zs+1, pB0,pB1,pB2,pB3, qB0,qB1,qB2,qB3)
        LOADO(zs+3, pB0,pB1,pB2,pB3, qB0,qB1,qB2,qB3)
      }
      STEPX(KC-2, pA0,pA1,pA2,pA3, qA0,qA1,qA2,qA3)
      STEPX(KC-1, pB0,pB1,pB2,pB3, qB0,qB1,qB2,qB3)
    } else {
      // tail round (last round of last bz): r15 simple path
      for (int zs = 0; zs < zc; ++zs) {
        bf16x8 b8 = *(const bf16x8*)&Wsh[buf][lr*SLDS + zs*32 + lg*8];
        const int kk = (zr0 + zs)*32 + lg*8;
        const int h = kk / 712;
        const int t = kk - h*712;
        #pragma unroll
        for (int rf = 0; rf < 4; rf++) {
          const int n = n0 + rf*16 + lr;
          bf16x8 o8 = *(const bf16x8*)&ob[(size_t)n*712 + t];
          const float sv = sT[h*256 + n];
          bf16x8 a8;
          #pragma unroll
          for (int i = 0; i < 8; i++) a8[i] = (__bf16)(sv * (float)o8[i]);
          acc[rf] = __builtin_amdgcn_mfma_f32_16x16x32_bf16(a8, b8, acc[rf], 0, 0, 0);
        }
      }
    }
#undef LOADO
#undef STEPX

    if (r + 1 < nrounds) {
      stage_store((r+1)&1);          // writes buffer NOT being computed
      __syncthreads();
      if (r + 2 < nrounds) stage_load(r+2);
    }
  }

  // ---- epilogue: partials [bz][256][712] (D: col=lane&15, row=(lane>>4)*4+i)
  if (myc < 712) {
    #pragma unroll
    for (int rf = 0; rf < 4; rf++) {
      #pragma unroll
      for (int i = 0; i < 4; i++) {
        const int n = n0 + rf*16 + lg*4 + i;
        part[((size_t)bz*256 + n)*712 + myc] = acc[rf][i];
      }
    }
  }
}

struct GP {
  const float* A; const float* A2; const float* B; const float* bias;
  float* C;
  const int* gidx; int goff;
  int M, N, K;
  int ldc, coff;
  int kChunk;
  const float* bn_g; const float* bn_b; const float* bn_m; const float* bn_v;
  const float* B2; const float* bias2; float* C2;   // mode 0 pair-merge
};

// modes:
// 0: A gathered via gidx col=blockIdx.z; B/bias/C selected by blockIdx.z
// 2: plain A (ubuf rows), plain B (vr_w)        epi: partial C[z][M][N]
// 3: A = concat(s,o)                            epi: partial C[z][M][N]
// 4: A = relu(concat(z1,bil))                   epi: partial C[z][M][N]
// 5: A = union_feat gather [(n,q)][ic]          epi: +bias -> ubuf[n][oc][q]
// 6: A = im2col(xp) 3x3 pad1                    epi: bn2(relu(+bias)) += ubuf[n][oc][q]
// 8: plain A                                    epi: sigmoid(+bias) -> C

template<int MODE>
DEV float loadA(const GP& p, int r, int k) {
  if (MODE == 0) { int fr = p.gidx[2*r + (int)blockIdx.z]; return p.A[fr*2048 + k]; }
  if (MODE == 2 || MODE == 8) return p.A[r*p.K + k];
  if (MODE == 3) return (k < 712) ? p.A[r*712 + k] : p.A2[r*712 + (k-712)];
  if (MODE == 4) { float v = (k < 712) ? p.A[r*712 + k] : p.A2[r*712 + (k-712)];
                   return fmaxf(v, 0.f); }
  if (MODE == 5) { int n = r/49, q = r - n*49; return p.A[(n*1024 + k)*49 + q]; }
  if (MODE == 6) {
    int n = r/49, q = r - n*49; int py = q/7, px = q - py*7;
    int ic = k/9, k9 = k - ic*9; int dy = k9/3, dx = k9 - dy*3;
    int iy = py + dy - 1, ix = px + dx - 1;
    if ((unsigned)iy >= 7u || (unsigned)ix >= 7u) return 0.f;
    return p.A[(n*128 + ic)*49 + iy*7 + ix];
  }
  return 0.f;
}

template<int MODE>
DEV float loadB(const GP& p, int c, int k) {
  if (MODE == 0) { const float* Bp = blockIdx.z ? p.B2 : p.B; return Bp[c*p.K + k]; }
  return p.B[c*p.K + k];
}

// ============================================================
// Generic GEMM, bf16-split MFMA (3-term, unchanged from r10-r21).
// ============================================================
template<int MODE>
__global__ __launch_bounds__(256) void gemm_k(GP p) {
  __shared__ __align__(16) __bf16 Ash[2][64*44];
  __shared__ __align__(16) __bf16 Bsh[2][64*44];
  const int tid = threadIdx.x;
  const int srow = tid & 63, koff = (tid >> 6) * 8;
  const int col0 = blockIdx.x * 64, row0 = blockIdx.y * 64;
  const int kStart = (MODE == 0) ? 0 : blockIdx.z * p.kChunk;
  const int kEnd = min(p.K, kStart + p.kChunk);
  const int wv = tid >> 6, lane = tid & 63;
  const int lr = lane & 15, lg = lane >> 4;
  const int rh = wv >> 1, ch = wv & 1;

  f32x4 acc[2][2];
  #pragma unroll
  for (int a = 0; a < 2; a++)
    #pragma unroll
    for (int b = 0; b < 2; b++) { acc[a][b][0]=0.f; acc[a][b][1]=0.f; acc[a][b][2]=0.f; acc[a][b][3]=0.f; }

  for (int kb = kStart; kb < kEnd; kb += 32) {
    {
      const int gr = row0 + srow;
      float v[8];
      #pragma unroll
      for (int i = 0; i < 8; i++) {
        const int gk = kb + koff + i;
        v[i] = (gr < p.M && gk < kEnd) ? loadA<MODE>(p, gr, gk) : 0.f;
      }
      bf16x8 hi, lo;
      #pragma unroll
      for (int i = 0; i < 8; i++) {
        __bf16 h = (__bf16)v[i];
        hi[i] = h;
        lo[i] = (__bf16)(v[i] - (float)h);
      }
      *(bf16x8*)&Ash[0][srow*44 + koff] = hi;
      *(bf16x8*)&Ash[1][srow*44 + koff] = lo;
    }
    {
      const int gc = col0 + srow;
      float v[8];
      #pragma unroll
      for (int i = 0; i < 8; i++) {
        const int gk = kb + koff + i;
        v[i] = (gc < p.N && gk < kEnd) ? loadB<MODE>(p, gc, gk) : 0.f;
      }
      bf16x8 hi, lo;
      #pragma unroll
      for (int i = 0; i < 8; i++) {
        __bf16 h = (__bf16)v[i];
        hi[i] = h;
        lo[i] = (__bf16)(v[i] - (float)h);
      }
      *(bf16x8*)&Bsh[0][srow*44 + koff] = hi;
      *(bf16x8*)&Bsh[1][srow*44 + koff] = lo;
    }
    __syncthreads();
    #pragma unroll
    for (int rf = 0; rf < 2; rf++) {
      bf16x8 ahi = *(const bf16x8*)&Ash[0][(rh*32 + rf*16 + lr)*44 + lg*8];
      bf16x8 alo = *(const bf16x8*)&Ash[1][(rh*32 + rf*16 + lr)*44 + lg*8];
      #pragma unroll
      for (int cf = 0; cf < 2; cf++) {
        bf16x8 bhi = *(const bf16x8*)&Bsh[0][(ch*32 + cf*16 + lr)*44 + lg*8];
        bf16x8 blo = *(const bf16x8*)&Bsh[1][(ch*32 + cf*16 + lr)*44 + lg*8];
        acc[rf][cf] = __builtin_amdgcn_mfma_f32_16x16x32_bf16(ahi, bhi, acc[rf][cf], 0, 0, 0);
        acc[rf][cf] = __builtin_amdgcn_mfma_f32_16x16x32_bf16(ahi, blo, acc[rf][cf], 0, 0, 0);
        acc[rf][cf] = __builtin_amdgcn_mfma_f32_16x16x32_bf16(alo, bhi, acc[rf][cf], 0, 0, 0);
      }
    }
    __syncthreads();
  }

  // ---- epilogue (D: col=lane&15, row=(lane>>4)*4+i) ----
  #pragma unroll
  for (int rf = 0; rf < 2; rf++) {
    #pragma unroll
    for (int cf = 0; cf < 2; cf++) {
      const int c = col0 + ch*32 + cf*16 + lr;
      if (c >= p.N) continue;
      #pragma unroll
      for (int i = 0; i < 4; i++) {
        const int r = row0 + rh*32 + rf*16 + lg*4 + i;
        if (r >= p.M) continue;
        float v = acc[rf][cf][i];
        if (MODE == 2 || MODE == 3 || MODE == 4) {
          p.C[(size_t)blockIdx.z * p.M * p.N + (size_t)r * p.N + c] = v;
        } else if (MODE == 5) {
          int n = r/49, q = r - n*49;
          p.C[n*12544 + c*49 + q] = v + p.bias[c];
        } else if (MODE == 6) {
          int n = r/49, q = r - n*49;
          float sc = p.bn_g[c] / sqrtf(p.bn_v[c] + 1e-5f);
          float sh = p.bn_b[c] - p.bn_m[c]*sc;
          float t2 = fmaxf(v + p.bias[c], 0.f)*sc + sh;
          p.C[n*12544 + c*49 + q] += t2;
        } else if (MODE == 8) {
          float t2 = v + p.bias[c];
          p.C[r*p.ldc + p.coff + c] = 1.f/(1.f + expf(-t2));
        } else {  // MODE 0: pair-merged subj/obj
          const float* bb = blockIdx.z ? p.bias2 : p.bias;
          float* Cp = blockIdx.z ? p.C2 : p.C;
          Cp[r*p.ldc + p.coff + c] = v + bb[c];
        }
      }
    }
  }
}

__global__ __launch_bounds__(256) void reduce_k(const float* __restrict__ part,
    const float* __restrict__ bias, float* __restrict__ out,
    int S, int MN, int N, int ldc, int coff) {
  int i = blockIdx.x*256 + threadIdx.x;
  if (i >= MN) return;
  float s = 0.f;
  for (int z = 0; z < S; z++) s += part[(size_t)z*MN + i];
  int r = i / N, c = i - r*N;
  out[r*ldc + coff + c] = s + bias[c];
}

__global__ __launch_bounds__(256) void emb_k(const int* __restrict__ pi,
    const int* __restrict__ labels, const float* __restrict__ e1,
    const float* __restrict__ e2, float* __restrict__ s, float* __restrict__ o) {
  int i = blockIdx.x*256 + threadIdx.x;
  if (i >= 2*256*200) return;
  int which = i / (256*200); int rest = i - which*(256*200);
  int n = rest / 200; int j = rest - n*200;
  int lab = labels[pi[2*n + which]];
  float v = which ? e2[lab*200 + j] : e1[lab*200 + j];
  (which ? o : s)[n*712 + 512 + j] = v;
}

__global__ __launch_bounds__(256) void conv1_k(const float* __restrict__ in,
    const float* __restrict__ w, const float* __restrict__ bias,
    const float* __restrict__ g, const float* __restrict__ bt,
    const float* __restrict__ m, const float* __restrict__ vv,
    float* __restrict__ out) {
  int idx = blockIdx.x*256 + threadIdx.x;
  if (idx >= 256*128*14) return;
  int oy = idx % 14; int t = idx / 14; int c = t & 127; int n = t >> 7;
  float acc[14];
  float b0 = bias[c];
  #pragma unroll
  for (int ox = 0; ox < 14; ox++) acc[ox] = b0;
  for (int ci = 0; ci < 2; ci++) {
    #pragma unroll
    for (int ky = 0; ky < 7; ky++) {
      int iy = oy*2 - 3 + ky;
      if ((unsigned)iy >= 27u) continue;
      const float* ir = in + ((n*2 + ci)*27 + iy)*27;
      const float* wr = w + ((c*2 + ci)*7 + ky)*7;
      float iv[27];
      #pragma unroll
      for (int x = 0; x < 27; x++) iv[x] = ir[x];
      float wk[7];
      #pragma unroll
      for (int kx = 0; kx < 7; kx++) wk[kx] = wr[kx];
      #pragma unroll
      for (int kx = 0; kx < 7; kx++)
        #pragma unroll
        for (int ox = 0; ox < 14; ox++) {
          int ix = ox*2 - 3 + kx;
          if (ix >= 0 && ix < 27) acc[ox] += iv[ix]*wk[kx];
        }
    }
  }
  float sc = g[c] / sqrtf(vv[c] + 1e-5f);
  float sh = bt[c] - m[c]*sc;
  float* orow = out + ((n*128 + c)*14 + oy)*14;
  #pragma unroll
  for (int ox = 0; ox < 14; ox++) orow[ox] = fmaxf(acc[ox], 0.f)*sc + sh;
}

__global__ __launch_bounds__(256) void pool_k(const float* __restrict__ x1,
                                              float* __restrict__ xp) {
  int idx = blockIdx.x*256 + threadIdx.x;
  if (idx >= 256*128*49) return;
  int px = idx % 7; int t = idx / 7; int py = t % 7; t /= 7;
  int c = t & 127; int n = t >> 7;
  float mx = -INFINITY;
  for (int dy = 0; dy < 3; dy++) {
    int y = py*2 - 1 + dy;
    if ((unsigned)y >= 14u) continue;
    for (int dx = 0; dx < 3; dx++) {
      int x = px*2 - 1 + dx;
      if ((unsigned)x >= 14u) continue;
      mx = fmaxf(mx, x1[((n*128 + c)*14 + y)*14 + x]);
    }
  }
  xp[((n*128 + c)*7 + py)*7 + px] = mx;
}

__global__ __launch_bounds__(256) void seg_k(const int* __restrict__ im,
    int* __restrict__ counts, int* __restrict__ starts, int* __restrict__ pos) {
  __shared__ int c[16], s[16];
  int tid = threadIdx.x;
  if (tid < 16) c[tid] = 0;
  __syncthreads();
  atomicAdd(&c[im[tid]], 1);
  __syncthreads();
  if (tid == 0) { int run = 0; for (int b = 0; b < 16; b++) { s[b] = run; run += c[b]; } }
  __syncthreads();
  if (tid < 16) { counts[tid] = c[tid]; starts[tid] = s[tid]; }
  pos[tid] = tid - s[im[tid]];
}

__global__ __launch_bounds__(256) void zeromask_k(float* __restrict__ out,
                                                  const int* __restrict__ counts) {
  int i = blockIdx.x*256 + threadIdx.x;
  if (i < SZ_MEM) { out[OFF_MEM + i] = 0.f; return; }
  int j = i - SZ_MEM;
  if (j < SZ_MASK) {
    int b = j / 24, l = j - b*24;
    out[OFF_MASK + j] = (l >= counts[b]) ? 1.f : 0.f;
  }
}

__global__ __launch_bounds__(256) void scatter_k(const float* __restrict__ rel,
    const int* __restrict__ pos, const int* __restrict__ im, float* __restrict__ out) {
  int n = blockIdx.x;
  int l = pos[n], b = im[n];
  float* dst = out + OFF_MEM + ((size_t)l*16 + b)*1936;
  const float* src = rel + (size_t)n*1936;
  for (int d = threadIdx.x; d < 1936; d += 256) dst[d] = src[d];
}

__global__ __launch_bounds__(256) void pooled_k(const float* __restrict__ rel,
    const int* __restrict__ starts, const int* __restrict__ counts,
    float* __restrict__ out) {
  int b = blockIdx.y;
  int d = blockIdx.x*256 + threadIdx.x;
  if (d >= 1936) return;
  int st = starts[b], ct = counts[b];
  float mx = -INFINITY;
  for (int i = 0; i < ct; i++) mx = fmaxf(mx, rel[(size_t)(st + i)*1936 + d]);
  out[OFF_POOLED + b*1936 + d] = mx;
}

extern "C" void kernel_launch(void* const* d_in, const int* in_sizes, int n_in,
                              void* d_out, int out_size, void* d_ws, size_t ws_size,
                              hipStream_t stream) {
  const float* features   = (const float*)d_in[0];
  const int*   pair_idx   = (const int*)d_in[1];
  const int*   im_idx     = (const int*)d_in[2];
  const int*   labels     = (const int*)d_in[3];
  const float* union_feat = (const float*)d_in[4];
  const float* spatial    = (const float*)d_in[5];
  const float* w_union    = (const float*)d_in[6];
  const float* b_union    = (const float*)d_in[7];
  const float* conv1_w    = (const float*)d_in[8];
  const float* conv1_b    = (const float*)d_in[9];
  const float* bn1_g      = (const float*)d_in[10];
  const float* bn1_b      = (const float*)d_in[11];
  const float* bn1_m      = (const float*)d_in[12];
  const float* bn1_v      = (const float*)d_in[13];
  const float* conv2_w    = (const float*)d_in[14];
  const float* conv2_b    = (const float*)d_in[15];
  const float* bn2_g      = (const float*)d_in[16];
  const float* bn2_b      = (const float*)d_in[17];
  const float* bn2_m      = (const float*)d_in[18];
  const float* bn2_v      = (const float*)d_in[19];
  const float* subj_w     = (const float*)d_in[20];
  const float* subj_b     = (const float*)d_in[21];
  const float* obj_w      = (const float*)d_in[22];
  const float* obj_b      = (const float*)d_in[23];
  const float* vr_w       = (const float*)d_in[24];
  const float* vr_b       = (const float*)d_in[25];
  const float* emb1       = (const float*)d_in[26];
  const float* emb2       = (const float*)d_in[27];
  const float* bil_w      = (const float*)d_in[28];
  const float* bil_b      = (const float*)d_in[29];
  const float* lin_w      = (const float*)d_in[30];
  const float* lin_b      = (const float*)d_in[31];
  const float* proj_w     = (const float*)d_in[32];
  const float* proj_b     = (const float*)d_in[33];
  const float* ac_w       = (const float*)d_in[34];
  const float* ac_b       = (const float*)d_in[35];

  float* ws = (float*)d_ws;
  float* s_mat  = ws + OFF_S;
  float* o_mat  = ws + OFF_O;
  float* z1     = ws + OFF_Z1;
  float* bilbuf = ws + OFF_BIL;
  float* rel    = ws + OFF_REL;
  float* ubuf   = ws + OFF_UBUF;   // layout [n][oc][q] = [256][256][49]
  float* x1     = ws + OFF_X1;
  float* xp     = ws + OFF_XP;
  float* pvr    = ws + OFF_PVR;
  float* pbil   = ws + OFF_PBIL;
  float* plin   = ws + OFF_PLIN;
  float* pproj  = ws + OFF_PPROJ;
  int*   ints   = (int*)(ws + OFF_INTS);
  __bf16* obp   = (__bf16*)(ws + OFF_OB);
  float* sTp    = ws + OFF_ST;
  int* counts = ints; int* starts = ints + 16; int* pos = ints + 32;
  float* out = (float*)d_out;

  dim3 blk(256);

  // subj + obj linears in ONE dispatch (blockIdx.z selects weights/output)
  {
    GP g{}; g.A = features; g.gidx = pair_idx;
    g.B = subj_w;  g.bias = subj_b;  g.C = s_mat;
    g.B2 = obj_w;  g.bias2 = obj_b;  g.C2 = o_mat;
    g.M = 256; g.N = 512; g.K = 2048; g.ldc = 712; g.coff = 0; g.kChunk = 2048;
    gemm_k<0><<<dim3(8,4,2), blk, 0, stream>>>(g);
  }
  // embedding concat -> cols [512,712)
  emb_k<<<dim3(400), blk, 0, stream>>>(pair_idx, labels, emb1, emb2, s_mat, o_mat);

  // union 1x1 conv as GEMM -> ubuf[n][oc][q] (scatter epilogue)
  {
    GP g{}; g.A = union_feat; g.B = w_union; g.bias = b_union; g.C = ubuf;
    g.M = 12544; g.N = 256; g.K = 1024; g.kChunk = 1024;
    gemm_k<5><<<dim3(4,196,1), blk, 0, stream>>>(g);
  }

  // conv1 + relu + bn1 -> x1 ; maxpool -> xp
  conv1_k<<<dim3(1792), blk, 0, stream>>>(spatial, conv1_w, conv1_b,
                                          bn1_g, bn1_b, bn1_m, bn1_v, x1);
  pool_k<<<dim3(6272), blk, 0, stream>>>(x1, xp);

  // conv2 (implicit GEMM) + relu + bn2, accumulated into ubuf[n][oc][q]
  {
    GP g{}; g.A = xp; g.B = conv2_w; g.bias = conv2_b; g.C = ubuf;
    g.M = 12544; g.N = 256; g.K = 1152; g.kChunk = 1152;
    g.bn_g = bn2_g; g.bn_b = bn2_b; g.bn_m = bn2_m; g.bn_v = bn2_v;
    gemm_k<6><<<dim3(4,196,1), blk, 0, stream>>>(g);
  }

  // vr linear: split-K 32 -> partials -> rel[:,1424:1936]
  {
    GP g{}; g.A = ubuf; g.B = vr_w; g.C = pvr;
    g.M = 256; g.N = 512; g.K = 12544; g.kChunk = 392;
    gemm_k<2><<<dim3(8,4,32), blk, 0, stream>>>(g);
    reduce_k<<<dim3(512), blk, 0, stream>>>(pvr, vr_b, rel, 32, 256*512, 512, 1936, 1424);
  }

  // lin: concat(s,o) @ lin_w^T, split-K 4 -> partials -> z1
  {
    GP g{}; g.A = s_mat; g.A2 = o_mat; g.B = lin_w; g.C = plin;
    g.M = 256; g.N = 712; g.K = 1424; g.kChunk = 356;
    gemm_k<3><<<dim3(12,4,4), blk, 0, stream>>>(g);
    reduce_k<<<dim3(712), blk, 0, stream>>>(plin, lin_b, z1, 4, 256*712, 712, 712, 0);
  }

  // bilinear: prep, burst-staged MFMA + ping-pong A-prefetch (grid 45x16)
  prep_k<<<dim3((256*712 + 712*256 + 255)/256), blk, 0, stream>>>(s_mat, o_mat, obp, sTp);
  bil_mfma_k<<<dim3(45, BSPLIT), blk, 0, stream>>>(obp, sTp, bil_w, pbil);
  reduce_k<<<dim3(712), blk, 0, stream>>>(pbil, bil_b, bilbuf, BSPLIT, 256*712, 712, 712, 0);

  // proj: relu(concat(z1,bil)) @ proj_w^T, split-K 2 -> partials -> rel[:,0:1424]
  {
    GP g{}; g.A = z1; g.A2 = bilbuf; g.B = proj_w; g.C = pproj;
    g.M = 256; g.N = 1424; g.K = 1424; g.kChunk = 712;
    gemm_k<4><<<dim3(23,4,2), blk, 0, stream>>>(g);
    reduce_k<<<dim3(1424), blk, 0, stream>>>(pproj, proj_b, rel, 2, 256*1424, 1424, 1936, 0);
  }

  // segments, memory zero + mask, scatter, pooled max
  seg_k<<<dim3(1), blk, 0, stream>>>(im_idx, counts, starts, pos);
  zeromask_k<<<dim3((SZ_MEM + SZ_MASK + 255)/256), blk, 0, stream>>>(out, counts);
  scatter_k<<<dim3(256), blk, 0, stream>>>(rel, pos, im_idx, out);
  pooled_k<<<dim3(8,16), blk, 0, stream>>>(rel, starts, counts, out);

  // act = sigmoid(pooled @ ac_w^T + ac_b)
  {
    GP g{}; g.A = out + OFF_POOLED; g.B = ac_w; g.bias = ac_b; g.C = out + OFF_ACT;
    g.M = 16; g.N = 157; g.K = 1936; g.ldc = 157; g.coff = 0; g.kChunk = 1936;
    gemm_k<8><<<dim3(3,1,1), blk, 0, stream>>>(g);
  }
}

// Round 24
// 1965.460 us; speedup vs baseline: 1.3720x; 1.0640x over previous
//
#include <hip/hip_runtime.h>
#include <math.h>

#define DEV __device__ __forceinline__

// ---- problem constants ----
#define PP    256          // pairs
#define BIMG  16
#define HB    712          // bilinear dim
#define KBIL  (712*712)    // 506944
#define DRELC 1936
// padded k-space: each h-panel padded 712 -> 736 = 23*32, so every
// 32-k z-step is h-UNIFORM (h = z/23). Total padded steps:
#define KSTEPS_P (712*23)  // 16376
#define BSPLIT 16          // bilinear split-K
#define ZPB    1024        // padded z-steps per split (16*1024 >= 16376; last 1016)
#define KC     16          // z-steps per staging round (512 padded k = 2KB/row)
#define SLDS   520         // LDS row stride in bf16 (1040 B)

// ---- d_out layout (floats) ----
#define SZ_ACT    (16*157)
#define OFF_ACT   0
#define OFF_POOLED (SZ_ACT)
#define SZ_POOLED (16*1936)
#define OFF_MEM   (OFF_POOLED + SZ_POOLED)
#define SZ_MEM    (24*16*1936)
#define OFF_MASK  (OFF_MEM + SZ_MEM)
#define SZ_MASK   (16*24)

// ---- ws layout (floats) ----
#define OFF_S     0
#define OFF_O     (OFF_S + 256*712)
#define OFF_Z1    (OFF_O + 256*712)
#define OFF_BIL   (OFF_Z1 + 256*712)
#define OFF_REL   (OFF_BIL + 256*712)
#define OFF_UBUF  (OFF_REL + 256*1936)
#define OFF_XP    (OFF_UBUF + 12544*256)
#define OFF_SHARED (OFF_XP + 256*128*49)
#define OFF_X1    OFF_SHARED                       // 256*128*196 floats
#define OFF_PVR   OFF_SHARED                       // 32*256*512 = 4.19M <= 6.42M
// pbil (16*256*712 = 2.92M floats) aliases ubuf region (dead by then);
// lin/proj partials too, consumed before pbil written (stream-ordered).
#define OFF_PBIL  OFF_UBUF
#define OFF_PLIN  OFF_UBUF
#define OFF_PPROJ OFF_UBUF
#define SZ_SHARED (256*128*196)                    // max(x1, pvr)
#define OFF_INTS  (OFF_SHARED + SZ_SHARED)
// bilinear prep buffers: o bf16 PADDED [256][736], sT f32 [712][256]
#define OFF_OB    (OFF_INTS + 256)                 // 256*736 bf16 = 94208 floats
#define OFF_ST    (OFF_OB + 94208)                 // 712*256 floats

typedef __bf16 bf16x4 __attribute__((ext_vector_type(4)));
typedef __bf16 bf16x8 __attribute__((ext_vector_type(8)));
typedef float  f32x4  __attribute__((ext_vector_type(4)));

// ============================================================
// prep: o -> bf16 padded [256][736] (zeros t>=712); s -> sT [712][256].
// ============================================================
__global__ __launch_bounds__(256) void prep_k(const float* __restrict__ s,
    const float* __restrict__ o, __bf16* __restrict__ ob, float* __restrict__ sT) {
  int i = blockIdx.x*256 + threadIdx.x;
  if (i < 256*736) {
    int n = i / 736, t = i - n*736;
    ob[i] = (__bf16)((t < 712) ? o[n*712 + t] : 0.f);
  } else {
    int j = i - 256*736;
    if (j < 712*256) {
      int h = j >> 8, n = j & 255;
      sT[j] = s[n*712 + h];
    }
  }
}

// ============================================================
// Bilinear v4 — r21 skeleton + PADDED-K DEFERRED RESCALE.
// k-space padded per h-panel to 736 = 23*32 -> every z-step is
// h-uniform (h = z/23, wave-uniform). Steps accumulate RAW
// gacc += mfma(o8, b8) — ZERO per-step VALU A-build (padded ob
// zeros kill pad-region W garbage). On wave-uniform h change:
// bacc += s[n,h]*gacc (16 FMA + 4 broadcast loads / ~23 steps).
// No per-lane straddle branch (r22's spill trap eliminated).
// Staging keeps the proven 2KB-burst pattern with a padded->real
// address map (clamped; garbage slots are A-zero-covered).
// Registers: st 32 + ping-pong 32 + gacc/bacc 32 + temps ~= 112.
// ============================================================
__global__ __launch_bounds__(256, 3) void bil_mfma_k(
    const __bf16* __restrict__ ob, const float* __restrict__ sT,
    const float* __restrict__ W, float* __restrict__ part) {
  __shared__ __align__(16) __bf16 Wsh[2][16*SLDS];   // 2 x 16.6 KB

  const int tid = threadIdx.x;
  const int wv = tid >> 6, lane = tid & 63;
  const int lr = lane & 15, lg = lane >> 4;
  const int c0 = blockIdx.x * 16;
  const int bz = blockIdx.y;
  const int zbase = bz * ZPB;
  const int zcntT = min(ZPB, KSTEPS_P - zbase);     // 1024 or 1016
  const int nrounds = (zcntT + KC - 1) / KC;

  // staging role: 16 threads per col-row; thread reads 8 x float4 (2KB/row)
  const int srow = tid >> 4;         // 0..15 = col within tile
  const int sl = tid & 15;
  const int scol = min(c0 + srow, 711);
  const float* wrow = W + (size_t)scol * KBIL;

  // compute role: wave wv owns rows [wv*64, wv*64+64), all 16 cols
  const int n0 = wv * 64;
  const int myc = c0 + lr;

  f32x4 gacc[4], bacc[4];
  #pragma unroll
  for (int rf = 0; rf < 4; rf++) {
    gacc[rf][0]=0.f; gacc[rf][1]=0.f; gacc[rf][2]=0.f; gacc[rf][3]=0.f;
    bacc[rf][0]=0.f; bacc[rf][1]=0.f; bacc[rf][2]=0.f; bacc[rf][3]=0.f;
  }
  int curh = zbase / 23;

  float4 st0, st1, st2, st3, st4, st5, st6, st7;
  auto stage_load = [&](int r) {
    const int kb = (zbase + r*KC) * 32 + sl*4;       // padded k index
    #define LD(J, DST) { int kp = kb + (J)*64; \
                         int h_ = kp / 736; \
                         int t_ = kp - h_*736; \
                         int hc = (h_ < 712) ? h_ : 711; \
                         int tc = (t_ < 712) ? t_ : 0; \
                         DST = *(const float4*)(wrow + (size_t)hc*712 + tc); }
    LD(0, st0) LD(1, st1) LD(2, st2) LD(3, st3)
    LD(4, st4) LD(5, st5) LD(6, st6) LD(7, st7)
    #undef LD
  };
  auto stage_store = [&](int buf) {
    __bf16* base = &Wsh[buf][srow*SLDS + sl*4];
    #define ST(J, SRC) { bf16x4 b; b[0]=(__bf16)SRC.x; b[1]=(__bf16)SRC.y; \
                         b[2]=(__bf16)SRC.z; b[3]=(__bf16)SRC.w; \
                         *(bf16x4*)(base + (J)*64) = b; }
    ST(0, st0) ST(1, st1) ST(2, st2) ST(3, st3)
    ST(4, st4) ST(5, st5) ST(6, st6) ST(7, st7)
    #undef ST
  };

#define FLUSH() { \
    f32x4 sv0 = *(const f32x4*)&sT[(size_t)curh*256 + n0 +  0 + lg*4]; \
    f32x4 sv1 = *(const f32x4*)&sT[(size_t)curh*256 + n0 + 16 + lg*4]; \
    f32x4 sv2 = *(const f32x4*)&sT[(size_t)curh*256 + n0 + 32 + lg*4]; \
    f32x4 sv3 = *(const f32x4*)&sT[(size_t)curh*256 + n0 + 48 + lg*4]; \
    _Pragma("unroll") \
    for (int i_ = 0; i_ < 4; i_++) { \
      bacc[0][i_] += sv0[i_]*gacc[0][i_]; gacc[0][i_] = 0.f; \
      bacc[1][i_] += sv1[i_]*gacc[1][i_]; gacc[1][i_] = 0.f; \
      bacc[2][i_] += sv2[i_]*gacc[2][i_]; gacc[2][i_] = 0.f; \
      bacc[3][i_] += sv3[i_]*gacc[3][i_]; gacc[3][i_] = 0.f; } }

  // ---- prologue ----
  stage_load(0);
  stage_store(0);
  if (nrounds > 1) stage_load(1);
  __syncthreads();

  // ---- main loop: one barrier per 16-step round ----
  for (int r = 0; r < nrounds; ++r) {
    const int zr0 = zbase + r*KC;
    const int zc = min(KC, zbase + zcntT - zr0);
    const int buf = r & 1;

#define LOADO(ZS, O0,O1,O2,O3) { \
      const int zp_ = zr0 + (ZS); \
      const int h_ = zp_ / 23; \
      const int tb_ = (zp_ - h_*23)*32 + lg*8; \
      O0 = *(const bf16x8*)&ob[(size_t)(n0 +  0 + lr)*736 + tb_]; \
      O1 = *(const bf16x8*)&ob[(size_t)(n0 + 16 + lr)*736 + tb_]; \
      O2 = *(const bf16x8*)&ob[(size_t)(n0 + 32 + lr)*736 + tb_]; \
      O3 = *(const bf16x8*)&ob[(size_t)(n0 + 48 + lr)*736 + tb_]; }

#define STEPX(ZS, O0,O1,O2,O3) { \
      bf16x8 b8 = *(const bf16x8*)&Wsh[buf][lr*SLDS + (ZS)*32 + lg*8]; \
      const int h_ = (zr0 + (ZS)) / 23; \
      if (h_ != curh) { FLUSH(); curh = h_; } \
      gacc[0] = __builtin_amdgcn_mfma_f32_16x16x32_bf16(O0, b8, gacc[0], 0, 0, 0); \
      gacc[1] = __builtin_amdgcn_mfma_f32_16x16x32_bf16(O1, b8, gacc[1], 0, 0, 0); \
      gacc[2] = __builtin_amdgcn_mfma_f32_16x16x32_bf16(O2, b8, gacc[2], 0, 0, 0); \
      gacc[3] = __builtin_amdgcn_mfma_f32_16x16x32_bf16(O3, b8, gacc[3], 0, 0, 0); }

    if (zc == KC) {
      // ping-pong prefetch: pure ob loads issued one step ahead
      bf16x8 pA0, pA1, pA2, pA3, pB0, pB1, pB2, pB3;
      LOADO(0, pA0,pA1,pA2,pA3)
      LOADO(1, pB0,pB1,pB2,pB3)
      for (int zs = 0; zs + 3 < KC; zs += 2) {
        STEPX(zs,   pA0,pA1,pA2,pA3)
        LOADO(zs+2, pA0,pA1,pA2,pA3)
        STEPX(zs+1, pB0,pB1,pB2,pB3)
        LOADO(zs+3, pB0,pB1,pB2,pB3)
      }
      STEPX(KC-2, pA0,pA1,pA2,pA3)
      STEPX(KC-1, pB0,pB1,pB2,pB3)
    } else {
      // tail round (last round of last bz)
      for (int zs = 0; zs < zc; ++zs) {
        bf16x8 t0, t1, t2, t3;
        LOADO(zs, t0,t1,t2,t3)
        STEPX(zs, t0,t1,t2,t3)
      }
    }
#undef LOADO
#undef STEPX

    if (r + 1 < nrounds) {
      stage_store((r+1)&1);          // writes buffer NOT being computed
      __syncthreads();
      if (r + 2 < nrounds) stage_load(r+2);
    }
  }

  FLUSH();                            // drain pending gacc
#undef FLUSH

  // ---- epilogue: partials [bz][256][712] (D: col=lane&15, row=(lane>>4)*4+i)
  if (myc < 712) {
    #pragma unroll
    for (int rf = 0; rf < 4; rf++) {
      #pragma unroll
      for (int i = 0; i < 4; i++) {
        const int n = n0 + rf*16 + lg*4 + i;
        part[((size_t)bz*256 + n)*712 + myc] = bacc[rf][i];
      }
    }
  }
}

struct GP {
  const float* A; const float* A2; const float* B; const float* bias;
  float* C;
  const int* gidx; int goff;
  int M, N, K;
  int ldc, coff;
  int kChunk;
  const float* bn_g; const float* bn_b; const float* bn_m; const float* bn_v;
  const float* B2; const float* bias2; float* C2;   // mode 0 pair-merge
};

// modes:
// 0: A gathered via gidx col=blockIdx.z; B/bias/C selected by blockIdx.z
// 2: plain A (ubuf rows), plain B (vr_w)        epi: partial C[z][M][N]
// 3: A = concat(s,o)                            epi: partial C[z][M][N]
// 4: A = relu(concat(z1,bil))                   epi: partial C[z][M][N]
// 5: A = union_feat gather [(n,q)][ic]          epi: +bias -> ubuf[n][oc][q]
// 6: A = im2col(xp) 3x3 pad1                    epi: bn2(relu(+bias)) += ubuf[n][oc][q]
// 8: plain A                                    epi: sigmoid(+bias) -> C

template<int MODE>
DEV float loadA(const GP& p, int r, int k) {
  if (MODE == 0) { int fr = p.gidx[2*r + (int)blockIdx.z]; return p.A[fr*2048 + k]; }
  if (MODE == 2 || MODE == 8) return p.A[r*p.K + k];
  if (MODE == 3) return (k < 712) ? p.A[r*712 + k] : p.A2[r*712 + (k-712)];
  if (MODE == 4) { float v = (k < 712) ? p.A[r*712 + k] : p.A2[r*712 + (k-712)];
                   return fmaxf(v, 0.f); }
  if (MODE == 5) { int n = r/49, q = r - n*49; return p.A[(n*1024 + k)*49 + q]; }
  if (MODE == 6) {
    int n = r/49, q = r - n*49; int py = q/7, px = q - py*7;
    int ic = k/9, k9 = k - ic*9; int dy = k9/3, dx = k9 - dy*3;
    int iy = py + dy - 1, ix = px + dx - 1;
    if ((unsigned)iy >= 7u || (unsigned)ix >= 7u) return 0.f;
    return p.A[(n*128 + ic)*49 + iy*7 + ix];
  }
  return 0.f;
}

template<int MODE>
DEV float loadB(const GP& p, int c, int k) {
  if (MODE == 0) { const float* Bp = blockIdx.z ? p.B2 : p.B; return Bp[c*p.K + k]; }
  return p.B[c*p.K + k];
}

// ============================================================
// Generic GEMM, bf16-split MFMA (3-term, unchanged from r10-r23).
// ============================================================
template<int MODE>
__global__ __launch_bounds__(256) void gemm_k(GP p) {
  __shared__ __align__(16) __bf16 Ash[2][64*44];
  __shared__ __align__(16) __bf16 Bsh[2][64*44];
  const int tid = threadIdx.x;
  const int srow = tid & 63, koff = (tid >> 6) * 8;
  const int col0 = blockIdx.x * 64, row0 = blockIdx.y * 64;
  const int kStart = (MODE == 0) ? 0 : blockIdx.z * p.kChunk;
  const int kEnd = min(p.K, kStart + p.kChunk);
  const int wv = tid >> 6, lane = tid & 63;
  const int lr = lane & 15, lg = lane >> 4;
  const int rh = wv >> 1, ch = wv & 1;

  f32x4 acc[2][2];
  #pragma unroll
  for (int a = 0; a < 2; a++)
    #pragma unroll
    for (int b = 0; b < 2; b++) { acc[a][b][0]=0.f; acc[a][b][1]=0.f; acc[a][b][2]=0.f; acc[a][b][3]=0.f; }

  for (int kb = kStart; kb < kEnd; kb += 32) {
    {
      const int gr = row0 + srow;
      float v[8];
      #pragma unroll
      for (int i = 0; i < 8; i++) {
        const int gk = kb + koff + i;
        v[i] = (gr < p.M && gk < kEnd) ? loadA<MODE>(p, gr, gk) : 0.f;
      }
      bf16x8 hi, lo;
      #pragma unroll
      for (int i = 0; i < 8; i++) {
        __bf16 h = (__bf16)v[i];
        hi[i] = h;
        lo[i] = (__bf16)(v[i] - (float)h);
      }
      *(bf16x8*)&Ash[0][srow*44 + koff] = hi;
      *(bf16x8*)&Ash[1][srow*44 + koff] = lo;
    }
    {
      const int gc = col0 + srow;
      float v[8];
      #pragma unroll
      for (int i = 0; i < 8; i++) {
        const int gk = kb + koff + i;
        v[i] = (gc < p.N && gk < kEnd) ? loadB<MODE>(p, gc, gk) : 0.f;
      }
      bf16x8 hi, lo;
      #pragma unroll
      for (int i = 0; i < 8; i++) {
        __bf16 h = (__bf16)v[i];
        hi[i] = h;
        lo[i] = (__bf16)(v[i] - (float)h);
      }
      *(bf16x8*)&Bsh[0][srow*44 + koff] = hi;
      *(bf16x8*)&Bsh[1][srow*44 + koff] = lo;
    }
    __syncthreads();
    #pragma unroll
    for (int rf = 0; rf < 2; rf++) {
      bf16x8 ahi = *(const bf16x8*)&Ash[0][(rh*32 + rf*16 + lr)*44 + lg*8];
      bf16x8 alo = *(const bf16x8*)&Ash[1][(rh*32 + rf*16 + lr)*44 + lg*8];
      #pragma unroll
      for (int cf = 0; cf < 2; cf++) {
        bf16x8 bhi = *(const bf16x8*)&Bsh[0][(ch*32 + cf*16 + lr)*44 + lg*8];
        bf16x8 blo = *(const bf16x8*)&Bsh[1][(ch*32 + cf*16 + lr)*44 + lg*8];
        acc[rf][cf] = __builtin_amdgcn_mfma_f32_16x16x32_bf16(ahi, bhi, acc[rf][cf], 0, 0, 0);
        acc[rf][cf] = __builtin_amdgcn_mfma_f32_16x16x32_bf16(ahi, blo, acc[rf][cf], 0, 0, 0);
        acc[rf][cf] = __builtin_amdgcn_mfma_f32_16x16x32_bf16(alo, bhi, acc[rf][cf], 0, 0, 0);
      }
    }
    __syncthreads();
  }

  // ---- epilogue (D: col=lane&15, row=(lane>>4)*4+i) ----
  #pragma unroll
  for (int rf = 0; rf < 2; rf++) {
    #pragma unroll
    for (int cf = 0; cf < 2; cf++) {
      const int c = col0 + ch*32 + cf*16 + lr;
      if (c >= p.N) continue;
      #pragma unroll
      for (int i = 0; i < 4; i++) {
        const int r = row0 + rh*32 + rf*16 + lg*4 + i;
        if (r >= p.M) continue;
        float v = acc[rf][cf][i];
        if (MODE == 2 || MODE == 3 || MODE == 4) {
          p.C[(size_t)blockIdx.z * p.M * p.N + (size_t)r * p.N + c] = v;
        } else if (MODE == 5) {
          int n = r/49, q = r - n*49;
          p.C[n*12544 + c*49 + q] = v + p.bias[c];
        } else if (MODE == 6) {
          int n = r/49, q = r - n*49;
          float sc = p.bn_g[c] / sqrtf(p.bn_v[c] + 1e-5f);
          float sh = p.bn_b[c] - p.bn_m[c]*sc;
          float t2 = fmaxf(v + p.bias[c], 0.f)*sc + sh;
          p.C[n*12544 + c*49 + q] += t2;
        } else if (MODE == 8) {
          float t2 = v + p.bias[c];
          p.C[r*p.ldc + p.coff + c] = 1.f/(1.f + expf(-t2));
        } else {  // MODE 0: pair-merged subj/obj
          const float* bb = blockIdx.z ? p.bias2 : p.bias;
          float* Cp = blockIdx.z ? p.C2 : p.C;
          Cp[r*p.ldc + p.coff + c] = v + bb[c];
        }
      }
    }
  }
}

__global__ __launch_bounds__(256) void reduce_k(const float* __restrict__ part,
    const float* __restrict__ bias, float* __restrict__ out,
    int S, int MN, int N, int ldc, int coff) {
  int i = blockIdx.x*256 + threadIdx.x;
  if (i >= MN) return;
  float s = 0.f;
  for (int z = 0; z < S; z++) s += part[(size_t)z*MN + i];
  int r = i / N, c = i - r*N;
  out[r*ldc + coff + c] = s + bias[c];
}

__global__ __launch_bounds__(256) void emb_k(const int* __restrict__ pi,
    const int* __restrict__ labels, const float* __restrict__ e1,
    const float* __restrict__ e2, float* __restrict__ s, float* __restrict__ o) {
  int i = blockIdx.x*256 + threadIdx.x;
  if (i >= 2*256*200) return;
  int which = i / (256*200); int rest = i - which*(256*200);
  int n = rest / 200; int j = rest - n*200;
  int lab = labels[pi[2*n + which]];
  float v = which ? e2[lab*200 + j] : e1[lab*200 + j];
  (which ? o : s)[n*712 + 512 + j] = v;
}

__global__ __launch_bounds__(256) void conv1_k(const float* __restrict__ in,
    const float* __restrict__ w, const float* __restrict__ bias,
    const float* __restrict__ g, const float* __restrict__ bt,
    const float* __restrict__ m, const float* __restrict__ vv,
    float* __restrict__ out) {
  int idx = blockIdx.x*256 + threadIdx.x;
  if (idx >= 256*128*14) return;
  int oy = idx % 14; int t = idx / 14; int c = t & 127; int n = t >> 7;
  float acc[14];
  float b0 = bias[c];
  #pragma unroll
  for (int ox = 0; ox < 14; ox++) acc[ox] = b0;
  for (int ci = 0; ci < 2; ci++) {
    #pragma unroll
    for (int ky = 0; ky < 7; ky++) {
      int iy = oy*2 - 3 + ky;
      if ((unsigned)iy >= 27u) continue;
      const float* ir = in + ((n*2 + ci)*27 + iy)*27;
      const float* wr = w + ((c*2 + ci)*7 + ky)*7;
      float iv[27];
      #pragma unroll
      for (int x = 0; x < 27; x++) iv[x] = ir[x];
      float wk[7];
      #pragma unroll
      for (int kx = 0; kx < 7; kx++) wk[kx] = wr[kx];
      #pragma unroll
      for (int kx = 0; kx < 7; kx++)
        #pragma unroll
        for (int ox = 0; ox < 14; ox++) {
          int ix = ox*2 - 3 + kx;
          if (ix >= 0 && ix < 27) acc[ox] += iv[ix]*wk[kx];
        }
    }
  }
  float sc = g[c] / sqrtf(vv[c] + 1e-5f);
  float sh = bt[c] - m[c]*sc;
  float* orow = out + ((n*128 + c)*14 + oy)*14;
  #pragma unroll
  for (int ox = 0; ox < 14; ox++) orow[ox] = fmaxf(acc[ox], 0.f)*sc + sh;
}

__global__ __launch_bounds__(256) void pool_k(const float* __restrict__ x1,
                                              float* __restrict__ xp) {
  int idx = blockIdx.x*256 + threadIdx.x;
  if (idx >= 256*128*49) return;
  int px = idx % 7; int t = idx / 7; int py = t % 7; t /= 7;
  int c = t & 127; int n = t >> 7;
  float mx = -INFINITY;
  for (int dy = 0; dy < 3; dy++) {
    int y = py*2 - 1 + dy;
    if ((unsigned)y >= 14u) continue;
    for (int dx = 0; dx < 3; dx++) {
      int x = px*2 - 1 + dx;
      if ((unsigned)x >= 14u) continue;
      mx = fmaxf(mx, x1[((n*128 + c)*14 + y)*14 + x]);
    }
  }
  xp[((n*128 + c)*7 + py)*7 + px] = mx;
}

__global__ __launch_bounds__(256) void seg_k(const int* __restrict__ im,
    int* __restrict__ counts, int* __restrict__ starts, int* __restrict__ pos) {
  __shared__ int c[16], s[16];
  int tid = threadIdx.x;
  if (tid < 16) c[tid] = 0;
  __syncthreads();
  atomicAdd(&c[im[tid]], 1);
  __syncthreads();
  if (tid == 0) { int run = 0; for (int b = 0; b < 16; b++) { s[b] = run; run += c[b]; } }
  __syncthreads();
  if (tid < 16) { counts[tid] = c[tid]; starts[tid] = s[tid]; }
  pos[tid] = tid - s[im[tid]];
}

__global__ __launch_bounds__(256) void zeromask_k(float* __restrict__ out,
                                                  const int* __restrict__ counts) {
  int i = blockIdx.x*256 + threadIdx.x;
  if (i < SZ_MEM) { out[OFF_MEM + i] = 0.f; return; }
  int j = i - SZ_MEM;
  if (j < SZ_MASK) {
    int b = j / 24, l = j - b*24;
    out[OFF_MASK + j] = (l >= counts[b]) ? 1.f : 0.f;
  }
}

__global__ __launch_bounds__(256) void scatter_k(const float* __restrict__ rel,
    const int* __restrict__ pos, const int* __restrict__ im, float* __restrict__ out) {
  int n = blockIdx.x;
  int l = pos[n], b = im[n];
  float* dst = out + OFF_MEM + ((size_t)l*16 + b)*1936;
  const float* src = rel + (size_t)n*1936;
  for (int d = threadIdx.x; d < 1936; d += 256) dst[d] = src[d];
}

__global__ __launch_bounds__(256) void pooled_k(const float* __restrict__ rel,
    const int* __restrict__ starts, const int* __restrict__ counts,
    float* __restrict__ out) {
  int b = blockIdx.y;
  int d = blockIdx.x*256 + threadIdx.x;
  if (d >= 1936) return;
  int st = starts[b], ct = counts[b];
  float mx = -INFINITY;
  for (int i = 0; i < ct; i++) mx = fmaxf(mx, rel[(size_t)(st + i)*1936 + d]);
  out[OFF_POOLED + b*1936 + d] = mx;
}

extern "C" void kernel_launch(void* const* d_in, const int* in_sizes, int n_in,
                              void* d_out, int out_size, void* d_ws, size_t ws_size,
                              hipStream_t stream) {
  const float* features   = (const float*)d_in[0];
  const int*   pair_idx   = (const int*)d_in[1];
  const int*   im_idx     = (const int*)d_in[2];
  const int*   labels     = (const int*)d_in[3];
  const float* union_feat = (const float*)d_in[4];
  const float* spatial    = (const float*)d_in[5];
  const float* w_union    = (const float*)d_in[6];
  const float* b_union    = (const float*)d_in[7];
  const float* conv1_w    = (const float*)d_in[8];
  const float* conv1_b    = (const float*)d_in[9];
  const float* bn1_g      = (const float*)d_in[10];
  const float* bn1_b      = (const float*)d_in[11];
  const float* bn1_m      = (const float*)d_in[12];
  const float* bn1_v      = (const float*)d_in[13];
  const float* conv2_w    = (const float*)d_in[14];
  const float* conv2_b    = (const float*)d_in[15];
  const float* bn2_g      = (const float*)d_in[16];
  const float* bn2_b      = (const float*)d_in[17];
  const float* bn2_m      = (const float*)d_in[18];
  const float* bn2_v      = (const float*)d_in[19];
  const float* subj_w     = (const float*)d_in[20];
  const float* subj_b     = (const float*)d_in[21];
  const float* obj_w      = (const float*)d_in[22];
  const float* obj_b      = (const float*)d_in[23];
  const float* vr_w       = (const float*)d_in[24];
  const float* vr_b       = (const float*)d_in[25];
  const float* emb1       = (const float*)d_in[26];
  const float* emb2       = (const float*)d_in[27];
  const float* bil_w      = (const float*)d_in[28];
  const float* bil_b      = (const float*)d_in[29];
  const float* lin_w      = (const float*)d_in[30];
  const float* lin_b      = (const float*)d_in[31];
  const float* proj_w     = (const float*)d_in[32];
  const float* proj_b     = (const float*)d_in[33];
  const float* ac_w       = (const float*)d_in[34];
  const float* ac_b       = (const float*)d_in[35];

  float* ws = (float*)d_ws;
  float* s_mat  = ws + OFF_S;
  float* o_mat  = ws + OFF_O;
  float* z1     = ws + OFF_Z1;
  float* bilbuf = ws + OFF_BIL;
  float* rel    = ws + OFF_REL;
  float* ubuf   = ws + OFF_UBUF;   // layout [n][oc][q] = [256][256][49]
  float* x1     = ws + OFF_X1;
  float* xp     = ws + OFF_XP;
  float* pvr    = ws + OFF_PVR;
  float* pbil   = ws + OFF_PBIL;
  float* plin   = ws + OFF_PLIN;
  float* pproj  = ws + OFF_PPROJ;
  int*   ints   = (int*)(ws + OFF_INTS);
  __bf16* obp   = (__bf16*)(ws + OFF_OB);
  float* sTp    = ws + OFF_ST;
  int* counts = ints; int* starts = ints + 16; int* pos = ints + 32;
  float* out = (float*)d_out;

  dim3 blk(256);

  // subj + obj linears in ONE dispatch (blockIdx.z selects weights/output)
  {
    GP g{}; g.A = features; g.gidx = pair_idx;
    g.B = subj_w;  g.bias = subj_b;  g.C = s_mat;
    g.B2 = obj_w;  g.bias2 = obj_b;  g.C2 = o_mat;
    g.M = 256; g.N = 512; g.K = 2048; g.ldc = 712; g.coff = 0; g.kChunk = 2048;
    gemm_k<0><<<dim3(8,4,2), blk, 0, stream>>>(g);
  }
  // embedding concat -> cols [512,712)
  emb_k<<<dim3(400), blk, 0, stream>>>(pair_idx, labels, emb1, emb2, s_mat, o_mat);

  // union 1x1 conv as GEMM -> ubuf[n][oc][q] (scatter epilogue)
  {
    GP g{}; g.A = union_feat; g.B = w_union; g.bias = b_union; g.C = ubuf;
    g.M = 12544; g.N = 256; g.K = 1024; g.kChunk = 1024;
    gemm_k<5><<<dim3(4,196,1), blk, 0, stream>>>(g);
  }

  // conv1 + relu + bn1 -> x1 ; maxpool -> xp
  conv1_k<<<dim3(1792), blk, 0, stream>>>(spatial, conv1_w, conv1_b,
                                          bn1_g, bn1_b, bn1_m, bn1_v, x1);
  pool_k<<<dim3(6272), blk, 0, stream>>>(x1, xp);

  // conv2 (implicit GEMM) + relu + bn2, accumulated into ubuf[n][oc][q]
  {
    GP g{}; g.A = xp; g.B = conv2_w; g.bias = conv2_b; g.C = ubuf;
    g.M = 12544; g.N = 256; g.K = 1152; g.kChunk = 1152;
    g.bn_g = bn2_g; g.bn_b = bn2_b; g.bn_m = bn2_m; g.bn_v = bn2_v;
    gemm_k<6><<<dim3(4,196,1), blk, 0, stream>>>(g);
  }

  // vr linear: split-K 32 -> partials -> rel[:,1424:1936]
  {
    GP g{}; g.A = ubuf; g.B = vr_w; g.C = pvr;
    g.M = 256; g.N = 512; g.K = 12544; g.kChunk = 392;
    gemm_k<2><<<dim3(8,4,32), blk, 0, stream>>>(g);
    reduce_k<<<dim3(512), blk, 0, stream>>>(pvr, vr_b, rel, 32, 256*512, 512, 1936, 1424);
  }

  // lin: concat(s,o) @ lin_w^T, split-K 4 -> partials -> z1
  {
    GP g{}; g.A = s_mat; g.A2 = o_mat; g.B = lin_w; g.C = plin;
    g.M = 256; g.N = 712; g.K = 1424; g.kChunk = 356;
    gemm_k<3><<<dim3(12,4,4), blk, 0, stream>>>(g);
    reduce_k<<<dim3(712), blk, 0, stream>>>(plin, lin_b, z1, 4, 256*712, 712, 712, 0);
  }

  // bilinear: prep (padded ob + sT), padded-k deferred-rescale MFMA
  prep_k<<<dim3((256*736 + 712*256 + 255)/256), blk, 0, stream>>>(s_mat, o_mat, obp, sTp);
  bil_mfma_k<<<dim3(45, BSPLIT), blk, 0, stream>>>(obp, sTp, bil_w, pbil);
  reduce_k<<<dim3(712), blk, 0, stream>>>(pbil, bil_b, bilbuf, BSPLIT, 256*712, 712, 712, 0);

  // proj: relu(concat(z1,bil)) @ proj_w^T, split-K 2 -> partials -> rel[:,0:1424]
  {
    GP g{}; g.A = z1; g.A2 = bilbuf; g.B = proj_w; g.C = pproj;
    g.M = 256; g.N = 1424; g.K = 1424; g.kChunk = 712;
    gemm_k<4><<<dim3(23,4,2), blk, 0, stream>>>(g);
    reduce_k<<<dim3(1424), blk, 0, stream>>>(pproj, proj_b, rel, 2, 256*1424, 1424, 1936, 0);
  }

  // segments, memory zero + mask, scatter, pooled max
  seg_k<<<dim3(1), blk, 0, stream>>>(im_idx, counts, starts, pos);
  zeromask_k<<<dim3((SZ_MEM + SZ_MASK + 255)/256), blk, 0, stream>>>(out, counts);
  scatter_k<<<dim3(256), blk, 0, stream>>>(rel, pos, im_idx, out);
  pooled_k<<<dim3(8,16), blk, 0, stream>>>(rel, starts, counts, out);

  // act = sigmoid(pooled @ ac_w^T + ac_b)
  {
    GP g{}; g.A = out + OFF_POOLED; g.B = ac_w; g.bias = ac_b; g.C = out + OFF_ACT;
    g.M = 16; g.N = 157; g.K = 1936; g.ldc = 157; g.coff = 0; g.kChunk = 1936;
    gemm_k<8><<<dim3(3,1,1), blk, 0, stream>>>(g);
  }
}